// Round 1
// baseline (2473.974 us; speedup 1.0000x reference)
//
#include <hip/hip_runtime.h>

// ---------------------------------------------------------------------------
// Fused conv3x3(SAME) + bias + relu + maxpool2x2 (stride 2).
// Block: 256 threads = 16x16 pooled pixels. Each thread owns one pooled pixel
// (= 2x2 pre-pool conv outputs), accumulating COG output channels.
// Input tile (34x34 incl. halo) for one input channel staged in LDS per ci.
// Weights for the block's COG output channels staged in LDS once.
// ---------------------------------------------------------------------------
template<int CIN, int COUT, int COG, int HIN>
__global__ __launch_bounds__(256) void conv_pool_k(
    const float* __restrict__ in, const float* __restrict__ w,
    const float* __restrict__ bias, float* __restrict__ out)
{
    constexpr int HOUT  = HIN / 2;       // pooled output size
    constexpr int TILES = HOUT / 16;     // tiles per spatial dim
    constexpr int NGRP  = COUT / COG;
    static_assert(COUT % COG == 0, "");
    static_assert(HOUT % 16 == 0, "");

    int blk  = blockIdx.x;
    int b    = blk / (TILES * TILES * NGRP);
    int rem  = blk % (TILES * TILES * NGRP);
    int grp  = rem / (TILES * TILES);
    int tile = rem % (TILES * TILES);
    int ty0  = (tile / TILES) * 16;      // pooled-coord tile origin
    int tx0  = (tile % TILES) * 16;
    int tid  = threadIdx.x;
    int lty  = tid >> 4, ltx = tid & 15;

    __shared__ float sIn[34 * 34];
    __shared__ float sW[COG * CIN * 9];

    for (int i = tid; i < COG * CIN * 9; i += 256)
        sW[i] = w[(size_t)grp * COG * CIN * 9 + i];

    float acc[COG][4];
#pragma unroll
    for (int i = 0; i < COG; ++i)
#pragma unroll
        for (int j = 0; j < 4; ++j) acc[i][j] = 0.f;

    const int gy0 = 2 * ty0 - 1;         // input row of sIn row 0
    const int gx0 = 2 * tx0 - 1;
    const size_t inB = (size_t)b * CIN * HIN * HIN;

    for (int ci = 0; ci < CIN; ++ci) {
        __syncthreads();
        const float* ip = in + inB + (size_t)ci * HIN * HIN;
        for (int idx = tid; idx < 34 * 34; idx += 256) {
            int row = idx / 34, col = idx - row * 34;
            int gy = gy0 + row, gx = gx0 + col;
            float v = 0.f;
            if ((unsigned)gy < (unsigned)HIN && (unsigned)gx < (unsigned)HIN)
                v = ip[gy * HIN + gx];
            sIn[idx] = v;
        }
        __syncthreads();

        float rr[4][4];
#pragma unroll
        for (int dy = 0; dy < 4; ++dy)
#pragma unroll
            for (int dx = 0; dx < 4; ++dx)
                rr[dy][dx] = sIn[(2 * lty + dy) * 34 + 2 * ltx + dx];

#pragma unroll
        for (int i = 0; i < COG; ++i) {
            const float* wp = &sW[(i * CIN + ci) * 9];
            float w00 = wp[0], w01 = wp[1], w02 = wp[2];
            float w10 = wp[3], w11 = wp[4], w12 = wp[5];
            float w20 = wp[6], w21 = wp[7], w22 = wp[8];
#pragma unroll
            for (int sy = 0; sy < 2; ++sy)
#pragma unroll
                for (int sx = 0; sx < 2; ++sx) {
                    acc[i][sy * 2 + sx] +=
                          rr[sy + 0][sx + 0] * w00 + rr[sy + 0][sx + 1] * w01 + rr[sy + 0][sx + 2] * w02
                        + rr[sy + 1][sx + 0] * w10 + rr[sy + 1][sx + 1] * w11 + rr[sy + 1][sx + 2] * w12
                        + rr[sy + 2][sx + 0] * w20 + rr[sy + 2][sx + 1] * w21 + rr[sy + 2][sx + 2] * w22;
                }
        }
    }

    // pool(relu(conv + b)) == relu(max4(conv) + b)  (bias commutes with max,
    // relu monotone)
    int py = ty0 + lty, px = tx0 + ltx;
#pragma unroll
    for (int i = 0; i < COG; ++i) {
        int co = grp * COG + i;
        float m = fmaxf(fmaxf(acc[i][0], acc[i][1]), fmaxf(acc[i][2], acc[i][3]));
        float v = fmaxf(m + bias[co], 0.f);
        out[(((size_t)b * COUT + co) * HOUT + py) * HOUT + px] = v;
    }
}

// ---------------------------------------------------------------------------
// Fused conv3x3(SAME) + bias + relu + spatial-sum (for the mean).
// Block: 256 threads = 16x16, each owning a 2x2 patch of conv outputs
// (tile = 32x32 outputs). Per-channel partial sums block-reduced, then one
// atomicAdd per (b, co) per block. Head kernel divides by H*W.
// ---------------------------------------------------------------------------
template<int CIN, int COUT, int COG, int H>
__global__ __launch_bounds__(256) void conv_mean_k(
    const float* __restrict__ in, const float* __restrict__ w,
    const float* __restrict__ bias, float* __restrict__ accum /* B x COUT */)
{
    constexpr int TILES = H / 32;
    constexpr int NGRP  = COUT / COG;
    static_assert(H % 32 == 0, "");

    int blk  = blockIdx.x;
    int b    = blk / (TILES * TILES * NGRP);
    int rem  = blk % (TILES * TILES * NGRP);
    int grp  = rem / (TILES * TILES);
    int tile = rem % (TILES * TILES);
    int ty0  = (tile / TILES) * 32;
    int tx0  = (tile % TILES) * 32;
    int tid  = threadIdx.x;
    int lty  = tid >> 4, ltx = tid & 15;

    __shared__ float sIn[34 * 34];
    __shared__ float sW[COG * CIN * 9];
    __shared__ float sRed[COG][4];

    for (int i = tid; i < COG * CIN * 9; i += 256)
        sW[i] = w[(size_t)grp * COG * CIN * 9 + i];

    float acc[COG][4];
#pragma unroll
    for (int i = 0; i < COG; ++i)
#pragma unroll
        for (int j = 0; j < 4; ++j) acc[i][j] = 0.f;

    const int gy0 = ty0 - 1;
    const int gx0 = tx0 - 1;
    const size_t inB = (size_t)b * CIN * H * H;

    for (int ci = 0; ci < CIN; ++ci) {
        __syncthreads();
        const float* ip = in + inB + (size_t)ci * H * H;
        for (int idx = tid; idx < 34 * 34; idx += 256) {
            int row = idx / 34, col = idx - row * 34;
            int gy = gy0 + row, gx = gx0 + col;
            float v = 0.f;
            if ((unsigned)gy < (unsigned)H && (unsigned)gx < (unsigned)H)
                v = ip[gy * H + gx];
            sIn[idx] = v;
        }
        __syncthreads();

        float rr[4][4];
#pragma unroll
        for (int dy = 0; dy < 4; ++dy)
#pragma unroll
            for (int dx = 0; dx < 4; ++dx)
                rr[dy][dx] = sIn[(2 * lty + dy) * 34 + 2 * ltx + dx];

#pragma unroll
        for (int i = 0; i < COG; ++i) {
            const float* wp = &sW[(i * CIN + ci) * 9];
            float w00 = wp[0], w01 = wp[1], w02 = wp[2];
            float w10 = wp[3], w11 = wp[4], w12 = wp[5];
            float w20 = wp[6], w21 = wp[7], w22 = wp[8];
#pragma unroll
            for (int sy = 0; sy < 2; ++sy)
#pragma unroll
                for (int sx = 0; sx < 2; ++sx) {
                    acc[i][sy * 2 + sx] +=
                          rr[sy + 0][sx + 0] * w00 + rr[sy + 0][sx + 1] * w01 + rr[sy + 0][sx + 2] * w02
                        + rr[sy + 1][sx + 0] * w10 + rr[sy + 1][sx + 1] * w11 + rr[sy + 1][sx + 2] * w12
                        + rr[sy + 2][sx + 0] * w20 + rr[sy + 2][sx + 1] * w21 + rr[sy + 2][sx + 2] * w22;
                }
        }
    }

#pragma unroll
    for (int i = 0; i < COG; ++i) {
        float bv = bias[grp * COG + i];
        float s = fmaxf(acc[i][0] + bv, 0.f) + fmaxf(acc[i][1] + bv, 0.f)
                + fmaxf(acc[i][2] + bv, 0.f) + fmaxf(acc[i][3] + bv, 0.f);
#pragma unroll
        for (int off = 32; off > 0; off >>= 1) s += __shfl_down(s, off);
        if ((tid & 63) == 0) sRed[i][tid >> 6] = s;
    }
    __syncthreads();
    if (tid < COG) {
        float t = sRed[tid][0] + sRed[tid][1] + sRed[tid][2] + sRed[tid][3];
        atomicAdd(&accum[(size_t)b * COUT + grp * COG + tid], t);
    }
}

// ---------------------------------------------------------------------------
// global_stats: one block per batch image (256x256 mask).
// ---------------------------------------------------------------------------
__global__ __launch_bounds__(256) void stats_k(const float* __restrict__ mask,
                                               float* __restrict__ stats)
{
    int b = blockIdx.x, tid = threadIdx.x;
    const float* m = mask + (size_t)b * 65536;
    float area = 0.f, si = 0.f, sj = 0.f;
    int mini = 1 << 20, maxi = -1, minj = 1 << 20, maxj = -1;
    for (int idx = tid; idx < 65536; idx += 256) {
        float v = m[idx];
        if (v != 0.f) {
            int i = idx >> 8, j = idx & 255;
            area += 1.f; si += (float)i; sj += (float)j;
            mini = min(mini, i); maxi = max(maxi, i);
            minj = min(minj, j); maxj = max(maxj, j);
        }
    }
#pragma unroll
    for (int off = 32; off > 0; off >>= 1) {
        area += __shfl_down(area, off);
        si   += __shfl_down(si, off);
        sj   += __shfl_down(sj, off);
        mini  = min(mini, __shfl_down(mini, off));
        maxi  = max(maxi, __shfl_down(maxi, off));
        minj  = min(minj, __shfl_down(minj, off));
        maxj  = max(maxj, __shfl_down(maxj, off));
    }
    __shared__ float rA[4], rI[4], rJ[4];
    __shared__ int   rmi[4], rMi[4], rmj[4], rMj[4];
    if ((tid & 63) == 0) {
        int wv = tid >> 6;
        rA[wv] = area; rI[wv] = si; rJ[wv] = sj;
        rmi[wv] = mini; rMi[wv] = maxi; rmj[wv] = minj; rMj[wv] = maxj;
    }
    __syncthreads();
    if (tid == 0) {
        area = rA[0] + rA[1] + rA[2] + rA[3];
        si   = rI[0] + rI[1] + rI[2] + rI[3];
        sj   = rJ[0] + rJ[1] + rJ[2] + rJ[3];
        mini = min(min(rmi[0], rmi[1]), min(rmi[2], rmi[3]));
        maxi = max(max(rMi[0], rMi[1]), max(rMi[2], rMi[3]));
        minj = min(min(rmj[0], rmj[1]), min(rmj[2], rmj[3]));
        maxj = max(max(rMj[0], rMj[1]), max(rMj[2], rMj[3]));
        float st[6];
        if (area > 0.f) {
            float safe = fmaxf(area, 1.f);
            float cy = si / safe, cx = sj / safe;
            float h = (float)(maxi - mini), ww = (float)(maxj - minj);
            st[0] = cy / 256.f; st[1] = cx / 256.f;
            st[2] = h / 256.f;  st[3] = ww / 256.f;
            st[4] = area / 65536.f; st[5] = h * ww / 65536.f;
        } else {
            for (int k = 0; k < 6; ++k) st[k] = 0.f;
        }
        for (int k = 0; k < 6; ++k) stats[b * 6 + k] = st[k];
    }
}

// ---------------------------------------------------------------------------
// Fused MLP head. One block per batch row, 256 threads.
// local_acc/shape_acc hold spatial SUMS (divide by 64*64 here).
// ---------------------------------------------------------------------------
__global__ __launch_bounds__(256) void head_k(
    const float* __restrict__ local_acc,  // B x 128
    const float* __restrict__ shape_acc,  // B x 64
    const float* __restrict__ stats,      // B x 6
    const float* __restrict__ gw, const float* __restrict__ gb,     // 16x6, 16
    const float* __restrict__ fpw1, const float* __restrict__ fpb1, // 128x80, 128
    const float* __restrict__ fpw2, const float* __restrict__ fpb2, // 64x128, 64
    const float* __restrict__ ffw1, const float* __restrict__ ffb1, // 256x192, 256
    const float* __restrict__ ffw2, const float* __restrict__ ffb2, // 256x256, 256
    float* __restrict__ out)              // B x 256
{
    int b = blockIdx.x, tid = threadIdx.x;
    __shared__ float comb[80], hid1[128], sf[64], fused[192], hid2[256];
    constexpr float INV = 1.f / 4096.f;

    if (tid < 64) comb[tid] = shape_acc[b * 64 + tid] * INV;
    if (tid >= 64 && tid < 80) {
        int co = tid - 64;
        float s = gb[co];
        for (int k = 0; k < 6; ++k) s += gw[co * 6 + k] * stats[b * 6 + k];
        comb[tid] = s;
    }
    __syncthreads();
    if (tid < 128) {
        float s = fpb1[tid];
        for (int k = 0; k < 80; ++k) s += fpw1[tid * 80 + k] * comb[k];
        hid1[tid] = fmaxf(s, 0.f);
    }
    __syncthreads();
    if (tid < 64) {
        float s = fpb2[tid];
        for (int k = 0; k < 128; ++k) s += fpw2[tid * 128 + k] * hid1[k];
        sf[tid] = s;
    }
    if (tid < 128) fused[tid] = local_acc[b * 128 + tid] * INV;
    __syncthreads();
    if (tid >= 128 && tid < 192) fused[tid] = sf[tid - 128];
    __syncthreads();
    {
        float s = ffb1[tid];
        for (int k = 0; k < 192; ++k) s += ffw1[tid * 192 + k] * fused[k];
        hid2[tid] = fmaxf(s, 0.f);
    }
    __syncthreads();
    {
        float s = ffb2[tid];
        for (int k = 0; k < 256; ++k) s += ffw2[tid * 256 + k] * hid2[k];
        out[(size_t)b * 256 + tid] = s;
    }
}

// ---------------------------------------------------------------------------
extern "C" void kernel_launch(void* const* d_in, const int* in_sizes, int n_in,
                              void* d_out, int out_size, void* d_ws, size_t ws_size,
                              hipStream_t stream)
{
    const float* x    = (const float*)d_in[0];
    const float* mask = (const float*)d_in[1];
    const float* lw1 = (const float*)d_in[2];  const float* lb1 = (const float*)d_in[3];
    const float* lw2 = (const float*)d_in[4];  const float* lb2 = (const float*)d_in[5];
    const float* lw3 = (const float*)d_in[6];  const float* lb3 = (const float*)d_in[7];
    const float* sw1 = (const float*)d_in[8];  const float* sb1 = (const float*)d_in[9];
    const float* sw2 = (const float*)d_in[10]; const float* sb2 = (const float*)d_in[11];
    const float* sw3 = (const float*)d_in[12]; const float* sb3 = (const float*)d_in[13];
    const float* gw  = (const float*)d_in[14]; const float* gb  = (const float*)d_in[15];
    const float* fpw1 = (const float*)d_in[16]; const float* fpb1 = (const float*)d_in[17];
    const float* fpw2 = (const float*)d_in[18]; const float* fpb2 = (const float*)d_in[19];
    const float* ffw1 = (const float*)d_in[20]; const float* ffb1 = (const float*)d_in[21];
    const float* ffw2 = (const float*)d_in[22]; const float* ffb2 = (const float*)d_in[23];
    float* out = (float*)d_out;

    char* ws = (char*)d_ws;
    float* bufA      = (float*)ws;                       // up to 134,217,728 B (h1 / s1)
    float* bufB      = (float*)(ws + 134217728);         // 67,108,864 B (h2 / s2)
    float* local_acc = (float*)(ws + 201326592);         // 64*128 floats
    float* shape_acc = (float*)(ws + 201359360);         // 64*64 floats
    float* statsb    = (float*)(ws + 201375744);         // 64*6 floats

    // zero the mean accumulators (poisoned / stale between replays)
    hipMemsetAsync(local_acc, 0, 32768 + 16384, stream);

    // ---- local branch ----
    // conv1: 1->32 @256 -> pool -> 128^2
    conv_pool_k<1, 32, 16, 256><<<64 * 64 * 2, 256, 0, stream>>>(x, lw1, lb1, bufA);
    // conv2: 32->64 @128 -> pool -> 64^2
    conv_pool_k<32, 64, 16, 128><<<64 * 16 * 4, 256, 0, stream>>>(bufA, lw2, lb2, bufB);
    // conv3: 64->128 @64 -> mean
    conv_mean_k<64, 128, 16, 64><<<64 * 4 * 8, 256, 0, stream>>>(bufB, lw3, lb3, local_acc);

    // ---- shape branch (reuses bufA/bufB after local branch no longer needs them) ----
    conv_pool_k<1, 16, 16, 256><<<64 * 64 * 1, 256, 0, stream>>>(mask, sw1, sb1, bufA);
    conv_pool_k<16, 32, 16, 128><<<64 * 16 * 2, 256, 0, stream>>>(bufA, sw2, sb2, bufB);
    conv_mean_k<32, 64, 16, 64><<<64 * 4 * 4, 256, 0, stream>>>(bufB, sw3, sb3, shape_acc);

    // ---- global stats + head ----
    stats_k<<<64, 256, 0, stream>>>(mask, statsb);
    head_k<<<64, 256, 0, stream>>>(local_acc, shape_acc, statsb, gw, gb,
                                   fpw1, fpb1, fpw2, fpb2, ffw1, ffb1, ffw2, ffb2, out);
}

// Round 2
// 2416.230 us; speedup vs baseline: 1.0239x; 1.0239x over previous
//
#include <hip/hip_runtime.h>

// ---------------------------------------------------------------------------
// Fused conv3x3(SAME) + bias + relu + maxpool2x2 (stride 2).
// 256 threads = 16x16 pooled pixels; each thread owns 2x2 conv outputs for
// COG output channels. Input staged in LDS (CCH channels per barrier, with
// register prefetch of the next chunk). Weights read via wave-uniform
// (scalar) loads from global -- no LDS weight stage.
// ---------------------------------------------------------------------------
template<int CIN, int COUT, int COG, int HIN>
__global__ __launch_bounds__(256, 4) void conv_pool_k(
    const float* __restrict__ in, const float* __restrict__ w,
    const float* __restrict__ bias, float* __restrict__ out)
{
    constexpr int HOUT  = HIN / 2;
    constexpr int TILES = HOUT / 16;
    constexpr int NGRP  = COUT / COG;
    constexpr int CCH   = (CIN >= 2) ? 2 : 1;   // channels staged per barrier
    constexpr int NCH   = CIN / CCH;
    constexpr int SELEM = CCH * 34 * 34;
    constexpr int LPT   = (SELEM + 255) / 256;  // staged loads per thread
    static_assert(COUT % COG == 0 && HOUT % 16 == 0 && CIN % CCH == 0, "");

    int blk  = blockIdx.x;
    int b    = blk / (TILES * TILES * NGRP);
    int rem  = blk % (TILES * TILES * NGRP);
    int grp  = rem / (TILES * TILES);
    int tile = rem % (TILES * TILES);
    int ty0  = (tile / TILES) * 16;
    int tx0  = (tile % TILES) * 16;
    int tid  = threadIdx.x;
    int lty  = tid >> 4, ltx = tid & 15;

    __shared__ float sIn[SELEM];

    float acc[COG][4];
#pragma unroll
    for (int i = 0; i < COG; ++i)
#pragma unroll
        for (int j = 0; j < 4; ++j) acc[i][j] = 0.f;

    const int gy0 = 2 * ty0 - 1;
    const int gx0 = 2 * tx0 - 1;
    const size_t inB = (size_t)b * CIN * HIN * HIN;
    const float* __restrict__ wq = w + (size_t)grp * COG * CIN * 9;

    float stg[LPT];
    auto stage_load = [&](int c0) {
#pragma unroll
        for (int k = 0; k < LPT; ++k) {
            int idx = tid + k * 256;
            float v = 0.f;
            if (idx < SELEM) {
                int c   = idx / (34 * 34);
                int r   = idx % (34 * 34);
                int row = r / 34, col = r - row * 34;
                int gy = gy0 + row, gx = gx0 + col;
                if ((unsigned)gy < (unsigned)HIN && (unsigned)gx < (unsigned)HIN)
                    v = in[inB + (size_t)(c0 + c) * HIN * HIN + gy * HIN + gx];
            }
            stg[k] = v;
        }
    };

    stage_load(0);
    for (int ch = 0; ch < NCH; ++ch) {
        __syncthreads();                       // prior readers of sIn done
#pragma unroll
        for (int k = 0; k < LPT; ++k) {
            int idx = tid + k * 256;
            if (idx < SELEM) sIn[idx] = stg[k];
        }
        __syncthreads();
        if (ch + 1 < NCH) stage_load((ch + 1) * CCH);  // overlap w/ compute

#pragma unroll
        for (int cc = 0; cc < CCH; ++cc) {
            const float* sc = &sIn[cc * 34 * 34];
            float rr[4][4];
#pragma unroll
            for (int dy = 0; dy < 4; ++dy) {
                float2 p0 = *(const float2*)&sc[(2 * lty + dy) * 34 + 2 * ltx];
                float2 p1 = *(const float2*)&sc[(2 * lty + dy) * 34 + 2 * ltx + 2];
                rr[dy][0] = p0.x; rr[dy][1] = p0.y; rr[dy][2] = p1.x; rr[dy][3] = p1.y;
            }
            int ci = ch * CCH + cc;
#pragma unroll
            for (int i = 0; i < COG; ++i) {
                const float* wp = wq + (i * CIN + ci) * 9;   // wave-uniform -> s_load
                float w00 = wp[0], w01 = wp[1], w02 = wp[2];
                float w10 = wp[3], w11 = wp[4], w12 = wp[5];
                float w20 = wp[6], w21 = wp[7], w22 = wp[8];
#pragma unroll
                for (int sy = 0; sy < 2; ++sy)
#pragma unroll
                    for (int sx = 0; sx < 2; ++sx) {
                        float a = acc[i][sy * 2 + sx];
                        a = fmaf(rr[sy + 0][sx + 0], w00, a);
                        a = fmaf(rr[sy + 0][sx + 1], w01, a);
                        a = fmaf(rr[sy + 0][sx + 2], w02, a);
                        a = fmaf(rr[sy + 1][sx + 0], w10, a);
                        a = fmaf(rr[sy + 1][sx + 1], w11, a);
                        a = fmaf(rr[sy + 1][sx + 2], w12, a);
                        a = fmaf(rr[sy + 2][sx + 0], w20, a);
                        a = fmaf(rr[sy + 2][sx + 1], w21, a);
                        a = fmaf(rr[sy + 2][sx + 2], w22, a);
                        acc[i][sy * 2 + sx] = a;
                    }
            }
        }
    }

    int py = ty0 + lty, px = tx0 + ltx;
#pragma unroll
    for (int i = 0; i < COG; ++i) {
        int co = grp * COG + i;
        float m = fmaxf(fmaxf(acc[i][0], acc[i][1]), fmaxf(acc[i][2], acc[i][3]));
        float v = fmaxf(m + bias[co], 0.f);
        out[(((size_t)b * COUT + co) * HOUT + py) * HOUT + px] = v;
    }
}

// ---------------------------------------------------------------------------
// Fused conv3x3(SAME) + bias + relu + spatial-sum (mean accumulated via
// one atomicAdd per (b,co) per block). Same staging/weight scheme.
// ---------------------------------------------------------------------------
template<int CIN, int COUT, int COG, int H>
__global__ __launch_bounds__(256, 4) void conv_mean_k(
    const float* __restrict__ in, const float* __restrict__ w,
    const float* __restrict__ bias, float* __restrict__ accum /* B x COUT */)
{
    constexpr int TILES = H / 32;
    constexpr int NGRP  = COUT / COG;
    constexpr int CCH   = (CIN >= 2) ? 2 : 1;
    constexpr int NCH   = CIN / CCH;
    constexpr int SELEM = CCH * 34 * 34;
    constexpr int LPT   = (SELEM + 255) / 256;
    static_assert(H % 32 == 0 && CIN % CCH == 0, "");

    int blk  = blockIdx.x;
    int b    = blk / (TILES * TILES * NGRP);
    int rem  = blk % (TILES * TILES * NGRP);
    int grp  = rem / (TILES * TILES);
    int tile = rem % (TILES * TILES);
    int ty0  = (tile / TILES) * 32;
    int tx0  = (tile % TILES) * 32;
    int tid  = threadIdx.x;
    int lty  = tid >> 4, ltx = tid & 15;

    __shared__ float sIn[SELEM];
    __shared__ float sRed[COG][4];

    float acc[COG][4];
#pragma unroll
    for (int i = 0; i < COG; ++i)
#pragma unroll
        for (int j = 0; j < 4; ++j) acc[i][j] = 0.f;

    const int gy0 = ty0 - 1;
    const int gx0 = tx0 - 1;
    const size_t inB = (size_t)b * CIN * H * H;
    const float* __restrict__ wq = w + (size_t)grp * COG * CIN * 9;

    float stg[LPT];
    auto stage_load = [&](int c0) {
#pragma unroll
        for (int k = 0; k < LPT; ++k) {
            int idx = tid + k * 256;
            float v = 0.f;
            if (idx < SELEM) {
                int c   = idx / (34 * 34);
                int r   = idx % (34 * 34);
                int row = r / 34, col = r - row * 34;
                int gy = gy0 + row, gx = gx0 + col;
                if ((unsigned)gy < (unsigned)H && (unsigned)gx < (unsigned)H)
                    v = in[inB + (size_t)(c0 + c) * H * H + gy * H + gx];
            }
            stg[k] = v;
        }
    };

    stage_load(0);
    for (int ch = 0; ch < NCH; ++ch) {
        __syncthreads();
#pragma unroll
        for (int k = 0; k < LPT; ++k) {
            int idx = tid + k * 256;
            if (idx < SELEM) sIn[idx] = stg[k];
        }
        __syncthreads();
        if (ch + 1 < NCH) stage_load((ch + 1) * CCH);

#pragma unroll
        for (int cc = 0; cc < CCH; ++cc) {
            const float* sc = &sIn[cc * 34 * 34];
            float rr[4][4];
#pragma unroll
            for (int dy = 0; dy < 4; ++dy) {
                float2 p0 = *(const float2*)&sc[(2 * lty + dy) * 34 + 2 * ltx];
                float2 p1 = *(const float2*)&sc[(2 * lty + dy) * 34 + 2 * ltx + 2];
                rr[dy][0] = p0.x; rr[dy][1] = p0.y; rr[dy][2] = p1.x; rr[dy][3] = p1.y;
            }
            int ci = ch * CCH + cc;
#pragma unroll
            for (int i = 0; i < COG; ++i) {
                const float* wp = wq + (i * CIN + ci) * 9;
                float w00 = wp[0], w01 = wp[1], w02 = wp[2];
                float w10 = wp[3], w11 = wp[4], w12 = wp[5];
                float w20 = wp[6], w21 = wp[7], w22 = wp[8];
#pragma unroll
                for (int sy = 0; sy < 2; ++sy)
#pragma unroll
                    for (int sx = 0; sx < 2; ++sx) {
                        float a = acc[i][sy * 2 + sx];
                        a = fmaf(rr[sy + 0][sx + 0], w00, a);
                        a = fmaf(rr[sy + 0][sx + 1], w01, a);
                        a = fmaf(rr[sy + 0][sx + 2], w02, a);
                        a = fmaf(rr[sy + 1][sx + 0], w10, a);
                        a = fmaf(rr[sy + 1][sx + 1], w11, a);
                        a = fmaf(rr[sy + 1][sx + 2], w12, a);
                        a = fmaf(rr[sy + 2][sx + 0], w20, a);
                        a = fmaf(rr[sy + 2][sx + 1], w21, a);
                        a = fmaf(rr[sy + 2][sx + 2], w22, a);
                        acc[i][sy * 2 + sx] = a;
                    }
            }
        }
    }

#pragma unroll
    for (int i = 0; i < COG; ++i) {
        float bv = bias[grp * COG + i];
        float s = fmaxf(acc[i][0] + bv, 0.f) + fmaxf(acc[i][1] + bv, 0.f)
                + fmaxf(acc[i][2] + bv, 0.f) + fmaxf(acc[i][3] + bv, 0.f);
#pragma unroll
        for (int off = 32; off > 0; off >>= 1) s += __shfl_down(s, off);
        if ((tid & 63) == 0) sRed[i][tid >> 6] = s;
    }
    __syncthreads();
    if (tid < COG) {
        float t = sRed[tid][0] + sRed[tid][1] + sRed[tid][2] + sRed[tid][3];
        atomicAdd(&accum[(size_t)b * COUT + grp * COG + tid], t);
    }
}

// ---------------------------------------------------------------------------
// global_stats: one block per batch image (256x256 mask).
// ---------------------------------------------------------------------------
__global__ __launch_bounds__(256) void stats_k(const float* __restrict__ mask,
                                               float* __restrict__ stats)
{
    int b = blockIdx.x, tid = threadIdx.x;
    const float* m = mask + (size_t)b * 65536;
    float area = 0.f, si = 0.f, sj = 0.f;
    int mini = 1 << 20, maxi = -1, minj = 1 << 20, maxj = -1;
    for (int idx = tid; idx < 65536; idx += 256) {
        float v = m[idx];
        if (v != 0.f) {
            int i = idx >> 8, j = idx & 255;
            area += 1.f; si += (float)i; sj += (float)j;
            mini = min(mini, i); maxi = max(maxi, i);
            minj = min(minj, j); maxj = max(maxj, j);
        }
    }
#pragma unroll
    for (int off = 32; off > 0; off >>= 1) {
        area += __shfl_down(area, off);
        si   += __shfl_down(si, off);
        sj   += __shfl_down(sj, off);
        mini  = min(mini, __shfl_down(mini, off));
        maxi  = max(maxi, __shfl_down(maxi, off));
        minj  = min(minj, __shfl_down(minj, off));
        maxj  = max(maxj, __shfl_down(maxj, off));
    }
    __shared__ float rA[4], rI[4], rJ[4];
    __shared__ int   rmi[4], rMi[4], rmj[4], rMj[4];
    if ((tid & 63) == 0) {
        int wv = tid >> 6;
        rA[wv] = area; rI[wv] = si; rJ[wv] = sj;
        rmi[wv] = mini; rMi[wv] = maxi; rmj[wv] = minj; rMj[wv] = maxj;
    }
    __syncthreads();
    if (tid == 0) {
        area = rA[0] + rA[1] + rA[2] + rA[3];
        si   = rI[0] + rI[1] + rI[2] + rI[3];
        sj   = rJ[0] + rJ[1] + rJ[2] + rJ[3];
        mini = min(min(rmi[0], rmi[1]), min(rmi[2], rmi[3]));
        maxi = max(max(rMi[0], rMi[1]), max(rMi[2], rMi[3]));
        minj = min(min(rmj[0], rmj[1]), min(rmj[2], rmj[3]));
        maxj = max(max(rMj[0], rMj[1]), max(rMj[2], rMj[3]));
        float st[6];
        if (area > 0.f) {
            float safe = fmaxf(area, 1.f);
            float cy = si / safe, cx = sj / safe;
            float h = (float)(maxi - mini), ww = (float)(maxj - minj);
            st[0] = cy / 256.f; st[1] = cx / 256.f;
            st[2] = h / 256.f;  st[3] = ww / 256.f;
            st[4] = area / 65536.f; st[5] = h * ww / 65536.f;
        } else {
            for (int k = 0; k < 6; ++k) st[k] = 0.f;
        }
        for (int k = 0; k < 6; ++k) stats[b * 6 + k] = st[k];
    }
}

// ---------------------------------------------------------------------------
// Fused MLP head. One block per batch row, 256 threads.
// ---------------------------------------------------------------------------
__global__ __launch_bounds__(256) void head_k(
    const float* __restrict__ local_acc,  // B x 128 (spatial sums)
    const float* __restrict__ shape_acc,  // B x 64  (spatial sums)
    const float* __restrict__ stats,      // B x 6
    const float* __restrict__ gw, const float* __restrict__ gb,
    const float* __restrict__ fpw1, const float* __restrict__ fpb1,
    const float* __restrict__ fpw2, const float* __restrict__ fpb2,
    const float* __restrict__ ffw1, const float* __restrict__ ffb1,
    const float* __restrict__ ffw2, const float* __restrict__ ffb2,
    float* __restrict__ out)              // B x 256
{
    int b = blockIdx.x, tid = threadIdx.x;
    __shared__ float comb[80], hid1[128], sf[64], fused[192], hid2[256];
    constexpr float INV = 1.f / 4096.f;

    if (tid < 64) comb[tid] = shape_acc[b * 64 + tid] * INV;
    if (tid >= 64 && tid < 80) {
        int co = tid - 64;
        float s = gb[co];
        for (int k = 0; k < 6; ++k) s += gw[co * 6 + k] * stats[b * 6 + k];
        comb[tid] = s;
    }
    __syncthreads();
    if (tid < 128) {
        float s = fpb1[tid];
        for (int k = 0; k < 80; ++k) s += fpw1[tid * 80 + k] * comb[k];
        hid1[tid] = fmaxf(s, 0.f);
    }
    __syncthreads();
    if (tid < 64) {
        float s = fpb2[tid];
        for (int k = 0; k < 128; ++k) s += fpw2[tid * 128 + k] * hid1[k];
        sf[tid] = s;
    }
    if (tid < 128) fused[tid] = local_acc[b * 128 + tid] * INV;
    __syncthreads();
    if (tid >= 128 && tid < 192) fused[tid] = sf[tid - 128];
    __syncthreads();
    {
        float s = ffb1[tid];
        for (int k = 0; k < 192; ++k) s += ffw1[tid * 192 + k] * fused[k];
        hid2[tid] = fmaxf(s, 0.f);
    }
    __syncthreads();
    {
        float s = ffb2[tid];
        for (int k = 0; k < 256; ++k) s += ffw2[tid * 256 + k] * hid2[k];
        out[(size_t)b * 256 + tid] = s;
    }
}

// ---------------------------------------------------------------------------
extern "C" void kernel_launch(void* const* d_in, const int* in_sizes, int n_in,
                              void* d_out, int out_size, void* d_ws, size_t ws_size,
                              hipStream_t stream)
{
    const float* x    = (const float*)d_in[0];
    const float* mask = (const float*)d_in[1];
    const float* lw1 = (const float*)d_in[2];  const float* lb1 = (const float*)d_in[3];
    const float* lw2 = (const float*)d_in[4];  const float* lb2 = (const float*)d_in[5];
    const float* lw3 = (const float*)d_in[6];  const float* lb3 = (const float*)d_in[7];
    const float* sw1 = (const float*)d_in[8];  const float* sb1 = (const float*)d_in[9];
    const float* sw2 = (const float*)d_in[10]; const float* sb2 = (const float*)d_in[11];
    const float* sw3 = (const float*)d_in[12]; const float* sb3 = (const float*)d_in[13];
    const float* gw  = (const float*)d_in[14]; const float* gb  = (const float*)d_in[15];
    const float* fpw1 = (const float*)d_in[16]; const float* fpb1 = (const float*)d_in[17];
    const float* fpw2 = (const float*)d_in[18]; const float* fpb2 = (const float*)d_in[19];
    const float* ffw1 = (const float*)d_in[20]; const float* ffb1 = (const float*)d_in[21];
    const float* ffw2 = (const float*)d_in[22]; const float* ffb2 = (const float*)d_in[23];
    float* out = (float*)d_out;

    char* ws = (char*)d_ws;
    float* bufA      = (float*)ws;                       // 134,217,728 B (h1 / s1)
    float* bufB      = (float*)(ws + 134217728);         // 67,108,864 B (h2 / s2)
    float* local_acc = (float*)(ws + 201326592);         // 64*128 floats
    float* shape_acc = (float*)(ws + 201359360);         // 64*64 floats
    float* statsb    = (float*)(ws + 201375744);         // 64*6 floats

    hipMemsetAsync(local_acc, 0, 32768 + 16384, stream);

    // ---- local branch ----
    conv_pool_k<1, 32, 16, 256><<<64 * 64 * 2, 256, 0, stream>>>(x, lw1, lb1, bufA);
    conv_pool_k<32, 64, 16, 128><<<64 * 16 * 4, 256, 0, stream>>>(bufA, lw2, lb2, bufB);
    conv_mean_k<64, 128, 16, 64><<<64 * 4 * 8, 256, 0, stream>>>(bufB, lw3, lb3, local_acc);

    // ---- shape branch ----
    conv_pool_k<1, 16, 16, 256><<<64 * 64 * 1, 256, 0, stream>>>(mask, sw1, sb1, bufA);
    conv_pool_k<16, 32, 16, 128><<<64 * 16 * 2, 256, 0, stream>>>(bufA, sw2, sb2, bufB);
    conv_mean_k<32, 64, 16, 64><<<64 * 4 * 4, 256, 0, stream>>>(bufB, sw3, sb3, shape_acc);

    // ---- global stats + head ----
    stats_k<<<64, 256, 0, stream>>>(mask, statsb);
    head_k<<<64, 256, 0, stream>>>(local_acc, shape_acc, statsb, gw, gb,
                                   fpw1, fpb1, fpw2, fpb2, ffw1, ffb1, ffw2, ffb2, out);
}

// Round 3
// 987.590 us; speedup vs baseline: 2.5051x; 2.4466x over previous
//
#include <hip/hip_runtime.h>

typedef _Float16 f16x8 __attribute__((ext_vector_type(8)));
typedef float    f32x4 __attribute__((ext_vector_type(4)));
typedef unsigned int  uint32;
typedef unsigned short ushort16;

// ---------------------------------------------------------------------------
// Weight prep: fp32 OIHW [COUT][CIN][3][3] -> f16 packed [chunk][tap][COUT][16]
// (each uint32 = 2 consecutive-ci f16; ci zero-padded to chunk*32)
// ---------------------------------------------------------------------------
template<int CIN, int COUT>
__global__ __launch_bounds__(256) void prep_w_k(const float* __restrict__ w,
                                                uint32* __restrict__ dst)
{
    constexpr int NCH = (CIN + 31) / 32;
    int t = blockIdx.x * 256 + threadIdx.x;
    if (t >= NCH * 9 * COUT * 16) return;
    int u = t & 15;
    int r = t >> 4;
    int co = r % COUT; r /= COUT;
    int tap = r % 9;
    int ch  = r / 9;
    int ci0 = ch * 32 + u * 2;
    float a = (ci0     < CIN) ? w[(co * CIN + ci0)     * 9 + tap] : 0.f;
    float b = (ci0 + 1 < CIN) ? w[(co * CIN + ci0 + 1) * 9 + tap] : 0.f;
    _Float16 ha = (_Float16)a, hb = (_Float16)b;
    ushort16 ua, ub;
    __builtin_memcpy(&ua, &ha, 2);
    __builtin_memcpy(&ub, &hb, 2);
    dst[t] = (uint32)ua | ((uint32)ub << 16);
}

// ---------------------------------------------------------------------------
// MFMA implicit-GEMM conv3x3(SAME) with fused epilogue.
//   POOL=true : bias+relu+maxpool2x2 -> out [B][COUT][H/2][H/2]
//   POOL=false: bias+relu+spatial-sum -> atomicAdd accum [B][COUT]
// Block: 256 thr (4 waves). Tile: 16x16 conv pixels x 32 co (grp).
// Per k-chunk (32 ci): input tile 18x18 staged fp32->f16 in LDS
// [pos(324)][ci(40 pad)]; weights [tap][co32][ci40]. Per tap: 9 shifted
// GEMMs via mfma_f32_16x16x32_f16. A: m=pixel-col (lane&15), k=ci
// ((lane>>4)*8+j). B: k=ci, n=co (lane&15). D: m=(lane>>4)*4+reg, n=lane&15.
// ---------------------------------------------------------------------------
template<int CIN, int COUT, int H, bool POOL>
__global__ __launch_bounds__(256, 3) void conv_mfma_k(
    const float* __restrict__ in, const uint32* __restrict__ wp,
    const float* __restrict__ bias, float* __restrict__ out)
{
    constexpr int TILES = H / 16;
    constexpr int NG    = COUT / 32;
    constexpr int NCH   = (CIN + 31) / 32;
    static_assert(H % 16 == 0 && COUT % 32 == 0, "");

    __shared__ _Float16 sA[324 * 40];     // 25,920 B
    __shared__ _Float16 sW[9 * 32 * 40];  // 23,040 B

    int blk  = blockIdx.x;
    int b    = blk / (TILES * TILES * NG);
    int rem  = blk % (TILES * TILES * NG);
    int grp  = rem / (TILES * TILES);
    int tile = rem % (TILES * TILES);
    int ty0  = (tile / TILES) * 16;
    int tx0  = (tile % TILES) * 16;
    int tid  = threadIdx.x;
    int wv   = tid >> 6;
    int l    = tid & 63;
    int cl   = l & 15;        // A pixel-col / B,D co-col
    int kg   = l >> 4;        // k-group
    int cog0 = grp * 32;

    f32x4 acc[4][2];
#pragma unroll
    for (int i = 0; i < 4; ++i)
#pragma unroll
        for (int n = 0; n < 2; ++n) acc[i][n] = (f32x4){0.f, 0.f, 0.f, 0.f};

    for (int ch = 0; ch < NCH; ++ch) {
        if (ch) __syncthreads();
        // ---- stage input tile (18x18 x 32ci), fp32 -> f16 ----
#pragma unroll
        for (int e = 0; e < 41; ++e) {
            int idx = e * 256 + tid;
            if (idx < 10368) {
                int ci  = idx / 324;
                int r2  = idx - ci * 324;
                int row = r2 / 18;
                int col = r2 - row * 18;
                int gy = ty0 - 1 + row, gx = tx0 - 1 + col;
                int cig = ch * 32 + ci;
                float v = 0.f;
                if ((unsigned)gy < (unsigned)H && (unsigned)gx < (unsigned)H && cig < CIN)
                    v = in[((size_t)(b * CIN + cig)) * (H * H) + gy * H + gx];
                sA[(row * 18 + col) * 40 + ci] = (_Float16)v;
            }
        }
        // ---- stage weights for this chunk: 9 taps x 32 co x 32 ci ----
#pragma unroll
        for (int e = 0; e < 18; ++e) {
            int idx = e * 256 + tid;
            if (idx < 4608) {
                int u   = idx & 15;
                int co  = (idx >> 4) & 31;
                int tap = idx >> 9;
                uint32 v = wp[((ch * 9 + tap) * COUT + cog0 + co) * 16 + u];
                *(uint32*)&sW[(tap * 32 + co) * 40 + u * 2] = v;
            }
        }
        __syncthreads();

        // ---- 9 shifted GEMMs ----
#pragma unroll
        for (int tap = 0; tap < 9; ++tap) {
            int dy = tap / 3, dx = tap % 3;
            f16x8 bf0 = *(const f16x8*)&sW[(tap * 32 + cl) * 40 + kg * 8];
            f16x8 bf1 = *(const f16x8*)&sW[(tap * 32 + 16 + cl) * 40 + kg * 8];
#pragma unroll
            for (int i = 0; i < 4; ++i) {
                int R = wv * 4 + i;
                f16x8 af = *(const f16x8*)&sA[((R + dy) * 18 + cl + dx) * 40 + kg * 8];
                acc[i][0] = __builtin_amdgcn_mfma_f32_16x16x32_f16(af, bf0, acc[i][0], 0, 0, 0);
                acc[i][1] = __builtin_amdgcn_mfma_f32_16x16x32_f16(af, bf1, acc[i][1], 0, 0, 0);
            }
        }
    }

    if (POOL) {
        constexpr int HO = H / 2;
        __syncthreads();                       // done reading sA; alias as fp32 out stage
        float* sOut = (float*)sA;              // [32co][68]
        float bv0 = bias[cog0 + cl], bv1 = bias[cog0 + 16 + cl];
#pragma unroll
        for (int nt = 0; nt < 2; ++nt) {
            float bv = nt ? bv1 : bv0;
#pragma unroll
            for (int i2 = 0; i2 < 2; ++i2)
#pragma unroll
                for (int j2 = 0; j2 < 2; ++j2) {
                    float m = fmaxf(fmaxf(acc[2 * i2][nt][2 * j2], acc[2 * i2][nt][2 * j2 + 1]),
                                    fmaxf(acc[2 * i2 + 1][nt][2 * j2], acc[2 * i2 + 1][nt][2 * j2 + 1]));
                    float v = fmaxf(m + bv, 0.f);
                    sOut[(nt * 16 + cl) * 68 + (wv * 2 + i2) * 8 + kg * 2 + j2] = v;
                }
        }
        __syncthreads();
        int co = tid >> 3, pr = tid & 7;       // 32 co x 8 rows
        int gco = cog0 + co;
        size_t base = ((size_t)(b * COUT + gco) * HO + (ty0 >> 1) + pr) * HO + (tx0 >> 1);
        const float* sp = &sOut[co * 68 + pr * 8];
        float4 o0 = make_float4(sp[0], sp[1], sp[2], sp[3]);
        float4 o1 = make_float4(sp[4], sp[5], sp[6], sp[7]);
        *(float4*)&out[base]     = o0;
        *(float4*)&out[base + 4] = o1;
    } else {
        float bv0 = bias[cog0 + cl], bv1 = bias[cog0 + 16 + cl];
        float s0 = 0.f, s1 = 0.f;
#pragma unroll
        for (int i = 0; i < 4; ++i)
#pragma unroll
            for (int r = 0; r < 4; ++r) {
                s0 += fmaxf(acc[i][0][r] + bv0, 0.f);
                s1 += fmaxf(acc[i][1][r] + bv1, 0.f);
            }
        s0 += __shfl_xor(s0, 16); s0 += __shfl_xor(s0, 32);
        s1 += __shfl_xor(s1, 16); s1 += __shfl_xor(s1, 32);
        if (kg == 0) {
            atomicAdd(&out[b * COUT + cog0 + cl], s0);
            atomicAdd(&out[b * COUT + cog0 + 16 + cl], s1);
        }
    }
}

// ---------------------------------------------------------------------------
// fp32 conv3x3 + bias + relu + maxpool2x2 for CIN=1 input layers.
// ---------------------------------------------------------------------------
template<int CIN, int COUT, int COG, int HIN>
__global__ __launch_bounds__(256, 4) void conv_pool_k(
    const float* __restrict__ in, const float* __restrict__ w,
    const float* __restrict__ bias, float* __restrict__ out)
{
    constexpr int HOUT  = HIN / 2;
    constexpr int TILES = HOUT / 16;
    constexpr int NGRP  = COUT / COG;
    constexpr int SELEM = 34 * 34;
    constexpr int LPT   = (SELEM + 255) / 256;
    static_assert(CIN == 1, "fp32 path only for CIN=1");

    int blk  = blockIdx.x;
    int b    = blk / (TILES * TILES * NGRP);
    int rem  = blk % (TILES * TILES * NGRP);
    int grp  = rem / (TILES * TILES);
    int tile = rem % (TILES * TILES);
    int ty0  = (tile / TILES) * 16;
    int tx0  = (tile % TILES) * 16;
    int tid  = threadIdx.x;
    int lty  = tid >> 4, ltx = tid & 15;

    __shared__ float sIn[SELEM];

    float acc[COG][4];
#pragma unroll
    for (int i = 0; i < COG; ++i)
#pragma unroll
        for (int j = 0; j < 4; ++j) acc[i][j] = 0.f;

    const int gy0 = 2 * ty0 - 1;
    const int gx0 = 2 * tx0 - 1;
    const size_t inB = (size_t)b * HIN * HIN;
    const float* __restrict__ wq = w + (size_t)grp * COG * 9;

#pragma unroll
    for (int k = 0; k < LPT; ++k) {
        int idx = tid + k * 256;
        if (idx < SELEM) {
            int row = idx / 34, col = idx - row * 34;
            int gy = gy0 + row, gx = gx0 + col;
            float v = 0.f;
            if ((unsigned)gy < (unsigned)HIN && (unsigned)gx < (unsigned)HIN)
                v = in[inB + gy * HIN + gx];
            sIn[idx] = v;
        }
    }
    __syncthreads();

    float rr[4][4];
#pragma unroll
    for (int dy = 0; dy < 4; ++dy) {
        float2 p0 = *(const float2*)&sIn[(2 * lty + dy) * 34 + 2 * ltx];
        float2 p1 = *(const float2*)&sIn[(2 * lty + dy) * 34 + 2 * ltx + 2];
        rr[dy][0] = p0.x; rr[dy][1] = p0.y; rr[dy][2] = p1.x; rr[dy][3] = p1.y;
    }
#pragma unroll
    for (int i = 0; i < COG; ++i) {
        const float* wpt = wq + i * 9;
        float w00 = wpt[0], w01 = wpt[1], w02 = wpt[2];
        float w10 = wpt[3], w11 = wpt[4], w12 = wpt[5];
        float w20 = wpt[6], w21 = wpt[7], w22 = wpt[8];
#pragma unroll
        for (int sy = 0; sy < 2; ++sy)
#pragma unroll
            for (int sx = 0; sx < 2; ++sx) {
                float a = acc[i][sy * 2 + sx];
                a = fmaf(rr[sy + 0][sx + 0], w00, a);
                a = fmaf(rr[sy + 0][sx + 1], w01, a);
                a = fmaf(rr[sy + 0][sx + 2], w02, a);
                a = fmaf(rr[sy + 1][sx + 0], w10, a);
                a = fmaf(rr[sy + 1][sx + 1], w11, a);
                a = fmaf(rr[sy + 1][sx + 2], w12, a);
                a = fmaf(rr[sy + 2][sx + 0], w20, a);
                a = fmaf(rr[sy + 2][sx + 1], w21, a);
                a = fmaf(rr[sy + 2][sx + 2], w22, a);
                acc[i][sy * 2 + sx] = a;
            }
    }

    int py = ty0 + lty, px = tx0 + ltx;
#pragma unroll
    for (int i = 0; i < COG; ++i) {
        int co = grp * COG + i;
        float m = fmaxf(fmaxf(acc[i][0], acc[i][1]), fmaxf(acc[i][2], acc[i][3]));
        float v = fmaxf(m + bias[co], 0.f);
        out[(((size_t)b * COUT + co) * HOUT + py) * HOUT + px] = v;
    }
}

// ---------------------------------------------------------------------------
// global_stats: one block per batch image (256x256 mask).
// ---------------------------------------------------------------------------
__global__ __launch_bounds__(256) void stats_k(const float* __restrict__ mask,
                                               float* __restrict__ stats)
{
    int b = blockIdx.x, tid = threadIdx.x;
    const float* m = mask + (size_t)b * 65536;
    float area = 0.f, si = 0.f, sj = 0.f;
    int mini = 1 << 20, maxi = -1, minj = 1 << 20, maxj = -1;
    for (int idx = tid; idx < 65536; idx += 256) {
        float v = m[idx];
        if (v != 0.f) {
            int i = idx >> 8, j = idx & 255;
            area += 1.f; si += (float)i; sj += (float)j;
            mini = min(mini, i); maxi = max(maxi, i);
            minj = min(minj, j); maxj = max(maxj, j);
        }
    }
#pragma unroll
    for (int off = 32; off > 0; off >>= 1) {
        area += __shfl_down(area, off);
        si   += __shfl_down(si, off);
        sj   += __shfl_down(sj, off);
        mini  = min(mini, __shfl_down(mini, off));
        maxi  = max(maxi, __shfl_down(maxi, off));
        minj  = min(minj, __shfl_down(minj, off));
        maxj  = max(maxj, __shfl_down(maxj, off));
    }
    __shared__ float rA[4], rI[4], rJ[4];
    __shared__ int   rmi[4], rMi[4], rmj[4], rMj[4];
    if ((tid & 63) == 0) {
        int w = tid >> 6;
        rA[w] = area; rI[w] = si; rJ[w] = sj;
        rmi[w] = mini; rMi[w] = maxi; rmj[w] = minj; rMj[w] = maxj;
    }
    __syncthreads();
    if (tid == 0) {
        area = rA[0] + rA[1] + rA[2] + rA[3];
        si   = rI[0] + rI[1] + rI[2] + rI[3];
        sj   = rJ[0] + rJ[1] + rJ[2] + rJ[3];
        mini = min(min(rmi[0], rmi[1]), min(rmi[2], rmi[3]));
        maxi = max(max(rMi[0], rMi[1]), max(rMi[2], rMi[3]));
        minj = min(min(rmj[0], rmj[1]), min(rmj[2], rmj[3]));
        maxj = max(max(rMj[0], rMj[1]), max(rMj[2], rMj[3]));
        float st[6];
        if (area > 0.f) {
            float safe = fmaxf(area, 1.f);
            float cy = si / safe, cx = sj / safe;
            float h = (float)(maxi - mini), ww = (float)(maxj - minj);
            st[0] = cy / 256.f; st[1] = cx / 256.f;
            st[2] = h / 256.f;  st[3] = ww / 256.f;
            st[4] = area / 65536.f; st[5] = h * ww / 65536.f;
        } else {
            for (int k = 0; k < 6; ++k) st[k] = 0.f;
        }
        for (int k = 0; k < 6; ++k) stats[b * 6 + k] = st[k];
    }
}

// ---------------------------------------------------------------------------
// Fused MLP head. One block per batch row, 256 threads.
// ---------------------------------------------------------------------------
__global__ __launch_bounds__(256) void head_k(
    const float* __restrict__ local_acc,  // B x 128 (spatial sums)
    const float* __restrict__ shape_acc,  // B x 64  (spatial sums)
    const float* __restrict__ stats,      // B x 6
    const float* __restrict__ gw, const float* __restrict__ gb,
    const float* __restrict__ fpw1, const float* __restrict__ fpb1,
    const float* __restrict__ fpw2, const float* __restrict__ fpb2,
    const float* __restrict__ ffw1, const float* __restrict__ ffb1,
    const float* __restrict__ ffw2, const float* __restrict__ ffb2,
    float* __restrict__ out)              // B x 256
{
    int b = blockIdx.x, tid = threadIdx.x;
    __shared__ float comb[80], hid1[128], sf[64], fused[192], hid2[256];
    constexpr float INV = 1.f / 4096.f;

    if (tid < 64) comb[tid] = shape_acc[b * 64 + tid] * INV;
    if (tid >= 64 && tid < 80) {
        int co = tid - 64;
        float s = gb[co];
        for (int k = 0; k < 6; ++k) s += gw[co * 6 + k] * stats[b * 6 + k];
        comb[tid] = s;
    }
    __syncthreads();
    if (tid < 128) {
        float s = fpb1[tid];
        for (int k = 0; k < 80; ++k) s += fpw1[tid * 80 + k] * comb[k];
        hid1[tid] = fmaxf(s, 0.f);
    }
    __syncthreads();
    if (tid < 64) {
        float s = fpb2[tid];
        for (int k = 0; k < 128; ++k) s += fpw2[tid * 128 + k] * hid1[k];
        sf[tid] = s;
    }
    if (tid < 128) fused[tid] = local_acc[b * 128 + tid] * INV;
    __syncthreads();
    if (tid >= 128 && tid < 192) fused[tid] = sf[tid - 128];
    __syncthreads();
    {
        float s = ffb1[tid];
        for (int k = 0; k < 192; ++k) s += ffw1[tid * 192 + k] * fused[k];
        hid2[tid] = fmaxf(s, 0.f);
    }
    __syncthreads();
    {
        float s = ffb2[tid];
        for (int k = 0; k < 256; ++k) s += ffw2[tid * 256 + k] * hid2[k];
        out[(size_t)b * 256 + tid] = s;
    }
}

// ---------------------------------------------------------------------------
extern "C" void kernel_launch(void* const* d_in, const int* in_sizes, int n_in,
                              void* d_out, int out_size, void* d_ws, size_t ws_size,
                              hipStream_t stream)
{
    const float* x    = (const float*)d_in[0];
    const float* mask = (const float*)d_in[1];
    const float* lw1 = (const float*)d_in[2];  const float* lb1 = (const float*)d_in[3];
    const float* lw2 = (const float*)d_in[4];  const float* lb2 = (const float*)d_in[5];
    const float* lw3 = (const float*)d_in[6];  const float* lb3 = (const float*)d_in[7];
    const float* sw1 = (const float*)d_in[8];  const float* sb1 = (const float*)d_in[9];
    const float* sw2 = (const float*)d_in[10]; const float* sb2 = (const float*)d_in[11];
    const float* sw3 = (const float*)d_in[12]; const float* sb3 = (const float*)d_in[13];
    const float* gw  = (const float*)d_in[14]; const float* gb  = (const float*)d_in[15];
    const float* fpw1 = (const float*)d_in[16]; const float* fpb1 = (const float*)d_in[17];
    const float* fpw2 = (const float*)d_in[18]; const float* fpb2 = (const float*)d_in[19];
    const float* ffw1 = (const float*)d_in[20]; const float* ffb1 = (const float*)d_in[21];
    const float* ffw2 = (const float*)d_in[22]; const float* ffb2 = (const float*)d_in[23];
    float* out = (float*)d_out;

    char* ws = (char*)d_ws;
    float*  bufA      = (float*)ws;                        // 134,217,728 B
    float*  bufB      = (float*)(ws + 134217728);          // 67,108,864 B
    float*  local_acc = (float*)(ws + 201326592);          // 32,768 B
    float*  shape_acc = (float*)(ws + 201359360);          // 16,384 B
    float*  statsb    = (float*)(ws + 201375744);          // 1,536 B
    uint32* wp2       = (uint32*)(ws + 201377280);         // 36,864 B
    uint32* wp3       = (uint32*)(ws + 201414144);         // 147,456 B
    uint32* wp2s      = (uint32*)(ws + 201561600);         // 18,432 B
    uint32* wp3s      = (uint32*)(ws + 201580032);         // 36,864 B

    // weight prep (f16 split) + accumulator zeroing
    prep_w_k<32, 64>  <<<36,  256, 0, stream>>>(lw2, wp2);
    prep_w_k<64, 128> <<<144, 256, 0, stream>>>(lw3, wp3);
    prep_w_k<16, 32>  <<<18,  256, 0, stream>>>(sw2, wp2s);
    prep_w_k<32, 64>  <<<36,  256, 0, stream>>>(sw3, wp3s);
    hipMemsetAsync(local_acc, 0, 32768 + 16384, stream);

    // ---- local branch ----
    conv_pool_k<1, 32, 16, 256><<<64 * 64 * 2, 256, 0, stream>>>(x, lw1, lb1, bufA);
    conv_mfma_k<32, 64, 128, true> <<<64 * 64 * 2, 256, 0, stream>>>(bufA, wp2, lb2, bufB);
    conv_mfma_k<64, 128, 64, false><<<64 * 16 * 4, 256, 0, stream>>>(bufB, wp3, lb3, local_acc);

    // ---- shape branch ----
    conv_pool_k<1, 16, 16, 256><<<64 * 64 * 1, 256, 0, stream>>>(mask, sw1, sb1, bufA);
    conv_mfma_k<16, 32, 128, true> <<<64 * 64 * 1, 256, 0, stream>>>(bufA, wp2s, sb2, bufB);
    conv_mfma_k<32, 64, 64, false> <<<64 * 16 * 2, 256, 0, stream>>>(bufB, wp3s, sb3, shape_acc);

    // ---- global stats + head ----
    stats_k<<<64, 256, 0, stream>>>(mask, statsb);
    head_k<<<64, 256, 0, stream>>>(local_acc, shape_acc, statsb, gw, gb,
                                   fpw1, fpb1, fpw2, fpb2, ffw1, ffb1, ffw2, ffb2, out);
}

// Round 4
// 288.391 us; speedup vs baseline: 8.5785x; 3.4245x over previous
//
#include <hip/hip_runtime.h>

typedef _Float16 f16x8 __attribute__((ext_vector_type(8)));
typedef float    f32x4 __attribute__((ext_vector_type(4)));

static __device__ inline f16x8 f16x8_zero() {
    f16x8 v;
#pragma unroll
    for (int j = 0; j < 8; ++j) v[j] = (_Float16)0.f;
    return v;
}

// ---------------------------------------------------------------------------
// Weight prep for conv1 (CIN=1, split-f16 full precision):
// W1[co][k], k=0..8: hi(w_tap k); 9..17: hi(w_tap k-9); 18..26: lo(w_tap k-18);
// 27..31: 0.   (pairs with A: k<9 -> x_hi, 9..17 -> x_lo, 18..26 -> x_hi)
// => sum = x_hi*w_hi + x_lo*w_hi + x_hi*w_lo  (error ~2^-22)
// ---------------------------------------------------------------------------
template<int COUT>
__global__ __launch_bounds__(256) void prep_w1_k(const float* __restrict__ w,
                                                 _Float16* __restrict__ dst)
{
    int t = blockIdx.x * 256 + threadIdx.x;
    if (t >= COUT * 32) return;
    int co = t >> 5, k = t & 31;
    _Float16 r = (_Float16)0.f;
    if (k < 27) {
        int q = k / 9, tap = k - q * 9;
        float wv = w[co * 9 + tap];
        _Float16 hi = (_Float16)wv;
        r = (q == 2) ? (_Float16)(wv - (float)hi) : hi;
    }
    dst[t] = r;
}

// ---------------------------------------------------------------------------
// Weight prep for convN layers: fp32 OIHW -> f16 [ch][tap][COUT][32k] (k zero-
// padded past CIN).
// ---------------------------------------------------------------------------
template<int CIN, int COUT>
__global__ __launch_bounds__(256) void prep_wN_k(const float* __restrict__ w,
                                                 _Float16* __restrict__ dst)
{
    constexpr int NCH = (CIN + 31) / 32;
    int t = blockIdx.x * 256 + threadIdx.x;
    if (t >= NCH * 9 * COUT * 32) return;
    int k = t & 31;
    int r = t >> 5;
    int co = r % COUT; r /= COUT;
    int tap = r % 9;
    int ch  = r / 9;
    int ci  = ch * 32 + k;
    dst[t] = (ci < CIN) ? (_Float16)w[(co * CIN + ci) * 9 + tap] : (_Float16)0.f;
}

// ---------------------------------------------------------------------------
// conv1: CIN=1 fp32 input [B][256][256] -> conv3x3+bias+relu+pool ->
// f16 NHWC out [B][128][128][COUT].  MFMA 16x16x32 with K = 27-term split
// (full fp32 accuracy).  Block: 256 thr / 4 waves = 16x16 conv-pixel tile.
// ---------------------------------------------------------------------------
template<int COUT>
__global__ __launch_bounds__(256) void conv1_mfma_k(
    const float* __restrict__ in, const _Float16* __restrict__ W1,
    const float* __restrict__ bias, _Float16* __restrict__ out)
{
    constexpr int H = 256, TILES = H / 16, NT = COUT / 16;

    __shared__ _Float16 sHL[972];   // [0,324)=hi, [324,648)=lo, [648,972)=zeros

    int blk  = blockIdx.x;
    int b    = blk / (TILES * TILES);
    int tile = blk % (TILES * TILES);
    int ty0  = (tile / TILES) * 16;
    int tx0  = (tile % TILES) * 16;
    int tid  = threadIdx.x;
    int wv   = tid >> 6, l = tid & 63, cl = l & 15, kg = l >> 4;

    for (int idx = tid; idx < 324; idx += 256) {
        int row = idx / 18, col = idx - row * 18;
        int gy = ty0 - 1 + row, gx = tx0 - 1 + col;
        float v = 0.f;
        if ((unsigned)gy < (unsigned)H && (unsigned)gx < (unsigned)H)
            v = in[((size_t)b * H + gy) * H + gx];
        _Float16 hi = (_Float16)v;
        sHL[idx]       = hi;
        sHL[324 + idx] = (_Float16)(v - (float)hi);
        sHL[648 + idx] = (_Float16)0.f;
    }
    __syncthreads();

    // per-lane A addressing: k = kg*8+j -> (region, tap)
    int off8[8];
#pragma unroll
    for (int j = 0; j < 8; ++j) {
        int k = kg * 8 + j;
        int q = k / 9;              // 0:hi 1:lo 2:hi 3:zero
        int t = k - q * 9;          // tap (for q==3, 0..4 -> reads zero region)
        int region = (q == 1) ? 1 : ((q == 3) ? 2 : 0);
        off8[j] = region * 324 + (t / 3) * 18 + (t % 3) + cl;
    }

    f16x8 bf[NT];
#pragma unroll
    for (int nt = 0; nt < NT; ++nt)
        bf[nt] = *(const f16x8*)&W1[(nt * 16 + cl) * 32 + kg * 8];

    f32x4 acc[4][NT];
#pragma unroll
    for (int i = 0; i < 4; ++i)
#pragma unroll
        for (int nt = 0; nt < NT; ++nt) acc[i][nt] = (f32x4){0.f, 0.f, 0.f, 0.f};

#pragma unroll
    for (int i = 0; i < 4; ++i) {
        int R = wv * 4 + i;
        f16x8 af;
#pragma unroll
        for (int j = 0; j < 8; ++j) af[j] = sHL[off8[j] + R * 18];
#pragma unroll
        for (int nt = 0; nt < NT; ++nt)
            acc[i][nt] = __builtin_amdgcn_mfma_f32_16x16x32_f16(af, bf[nt], acc[i][nt], 0, 0, 0);
    }

    // pooled epilogue: conv rows (wv*4+i), cols (kg*4+r); pool 2x2 in-lane
    int py0 = ty0 >> 1, px0 = tx0 >> 1;
#pragma unroll
    for (int nt = 0; nt < NT; ++nt) {
        float bv = bias[nt * 16 + cl];
#pragma unroll
        for (int i2 = 0; i2 < 2; ++i2)
#pragma unroll
            for (int j2 = 0; j2 < 2; ++j2) {
                float m = fmaxf(fmaxf(acc[2 * i2][nt][2 * j2], acc[2 * i2][nt][2 * j2 + 1]),
                                fmaxf(acc[2 * i2 + 1][nt][2 * j2], acc[2 * i2 + 1][nt][2 * j2 + 1]));
                float v = fmaxf(m + bv, 0.f);
                out[(((size_t)b * 128 + py0 + wv * 2 + i2) * 128 + px0 + kg * 2 + j2) * COUT
                    + nt * 16 + cl] = (_Float16)v;
            }
    }
}

// ---------------------------------------------------------------------------
// convN: f16 NHWC input [B][H][H][CIN] -> conv3x3+bias+relu, then
//   POOL=true : maxpool2x2 -> f16 NHWC out [B][H/2][H/2][COUT]
//   POOL=false: spatial-sum -> atomicAdd f32 accum [B][COUT]
// K chunked by 32 ci.  sA [324 pos][40 pad], sW [9 tap][32 co][40 pad].
// ---------------------------------------------------------------------------
template<int CIN, int COUT, int H, bool POOL>
__global__ __launch_bounds__(256, 3) void convN_mfma_k(
    const _Float16* __restrict__ in, const _Float16* __restrict__ wp,
    const float* __restrict__ bias, void* __restrict__ outv)
{
    constexpr int TILES = H / 16;
    constexpr int NG    = COUT / 32;
    constexpr int NCH   = (CIN + 31) / 32;
    constexpr int KU    = (CIN >= 32) ? 4 : CIN / 8;   // real 16B units per pos
    static_assert(H % 16 == 0 && COUT % 32 == 0, "");

    __shared__ _Float16 sA[324 * 40];     // 25,920 B
    __shared__ _Float16 sW[9 * 32 * 40];  // 23,040 B

    int blk  = blockIdx.x;
    int b    = blk / (TILES * TILES * NG);
    int rem  = blk % (TILES * TILES * NG);
    int grp  = rem / (TILES * TILES);
    int tile = rem % (TILES * TILES);
    int ty0  = (tile / TILES) * 16;
    int tx0  = (tile % TILES) * 16;
    int tid  = threadIdx.x;
    int wv   = tid >> 6, l = tid & 63, cl = l & 15, kg = l >> 4;
    int cog0 = grp * 32;

    f32x4 acc[4][2];
#pragma unroll
    for (int i = 0; i < 4; ++i)
#pragma unroll
        for (int n = 0; n < 2; ++n) acc[i][n] = (f32x4){0.f, 0.f, 0.f, 0.f};

    for (int ch = 0; ch < NCH; ++ch) {
        if (ch) __syncthreads();
        // ---- stage A: 324 pos x 4 16B-units (zero-fill pad/halo) ----
        for (int u = tid; u < 1296; u += 256) {
            int pos = u >> 2, q = u & 3;
            int row = pos / 18, col = pos - row * 18;
            int gy = ty0 - 1 + row, gx = tx0 - 1 + col;
            f16x8 v = f16x8_zero();
            if (q < KU && (unsigned)gy < (unsigned)H && (unsigned)gx < (unsigned)H)
                v = *(const f16x8*)&in[(((size_t)b * H + gy) * H + gx) * CIN + ch * 32 + q * 8];
            *(f16x8*)&sA[pos * 40 + q * 8] = v;
        }
        // ---- stage W: 9 taps x 32 co x 4 16B-units ----
        for (int u = tid; u < 1152; u += 256) {
            int q = u & 3, row = u >> 2;          // row = tap*32 + co
            int tap = row >> 5, co = row & 31;
            f16x8 v = *(const f16x8*)&wp[(((size_t)ch * 9 + tap) * COUT + cog0 + co) * 32 + q * 8];
            *(f16x8*)&sW[row * 40 + q * 8] = v;
        }
        __syncthreads();

#pragma unroll
        for (int tap = 0; tap < 9; ++tap) {
            int dy = tap / 3, dx = tap - dy * 3;
            f16x8 bf0 = *(const f16x8*)&sW[(tap * 32 + cl) * 40 + kg * 8];
            f16x8 bf1 = *(const f16x8*)&sW[(tap * 32 + 16 + cl) * 40 + kg * 8];
#pragma unroll
            for (int i = 0; i < 4; ++i) {
                int R = wv * 4 + i;
                f16x8 af = *(const f16x8*)&sA[((R + dy) * 18 + cl + dx) * 40 + kg * 8];
                acc[i][0] = __builtin_amdgcn_mfma_f32_16x16x32_f16(af, bf0, acc[i][0], 0, 0, 0);
                acc[i][1] = __builtin_amdgcn_mfma_f32_16x16x32_f16(af, bf1, acc[i][1], 0, 0, 0);
            }
        }
    }

    if (POOL) {
        _Float16* out = (_Float16*)outv;
        constexpr int HO = H / 2;
        int py0 = ty0 >> 1, px0 = tx0 >> 1;
#pragma unroll
        for (int nt = 0; nt < 2; ++nt) {
            float bv = bias[cog0 + nt * 16 + cl];
#pragma unroll
            for (int i2 = 0; i2 < 2; ++i2)
#pragma unroll
                for (int j2 = 0; j2 < 2; ++j2) {
                    float m = fmaxf(fmaxf(acc[2 * i2][nt][2 * j2], acc[2 * i2][nt][2 * j2 + 1]),
                                    fmaxf(acc[2 * i2 + 1][nt][2 * j2], acc[2 * i2 + 1][nt][2 * j2 + 1]));
                    float v = fmaxf(m + bv, 0.f);
                    out[(((size_t)b * HO + py0 + wv * 2 + i2) * HO + px0 + kg * 2 + j2) * COUT
                        + cog0 + nt * 16 + cl] = (_Float16)v;
                }
        }
    } else {
        float* accum = (float*)outv;
        float bv0 = bias[cog0 + cl], bv1 = bias[cog0 + 16 + cl];
        float s0 = 0.f, s1 = 0.f;
#pragma unroll
        for (int i = 0; i < 4; ++i)
#pragma unroll
            for (int r = 0; r < 4; ++r) {
                s0 += fmaxf(acc[i][0][r] + bv0, 0.f);
                s1 += fmaxf(acc[i][1][r] + bv1, 0.f);
            }
        s0 += __shfl_xor(s0, 16); s0 += __shfl_xor(s0, 32);
        s1 += __shfl_xor(s1, 16); s1 += __shfl_xor(s1, 32);
        if (kg == 0) {
            atomicAdd(&accum[b * COUT + cog0 + cl], s0);
            atomicAdd(&accum[b * COUT + cog0 + 16 + cl], s1);
        }
    }
}

// ---------------------------------------------------------------------------
// global_stats: one block per batch image (256x256 mask), float4 loads.
// ---------------------------------------------------------------------------
__global__ __launch_bounds__(256) void stats_k(const float* __restrict__ mask,
                                               float* __restrict__ stats)
{
    int b = blockIdx.x, tid = threadIdx.x;
    const float4* m4 = (const float4*)(mask + (size_t)b * 65536);
    float area = 0.f, si = 0.f, sj = 0.f;
    int mini = 1 << 20, maxi = -1, minj = 1 << 20, maxj = -1;
    for (int i4 = tid; i4 < 16384; i4 += 256) {
        float4 v = m4[i4];
        int base = i4 * 4;
        int i = base >> 8, j0 = base & 255;
        float vv[4] = {v.x, v.y, v.z, v.w};
#pragma unroll
        for (int q = 0; q < 4; ++q) {
            if (vv[q] != 0.f) {
                int j = j0 + q;
                area += 1.f; si += (float)i; sj += (float)j;
                mini = min(mini, i); maxi = max(maxi, i);
                minj = min(minj, j); maxj = max(maxj, j);
            }
        }
    }
#pragma unroll
    for (int off = 32; off > 0; off >>= 1) {
        area += __shfl_down(area, off);
        si   += __shfl_down(si, off);
        sj   += __shfl_down(sj, off);
        mini  = min(mini, __shfl_down(mini, off));
        maxi  = max(maxi, __shfl_down(maxi, off));
        minj  = min(minj, __shfl_down(minj, off));
        maxj  = max(maxj, __shfl_down(maxj, off));
    }
    __shared__ float rA[4], rI[4], rJ[4];
    __shared__ int   rmi[4], rMi[4], rmj[4], rMj[4];
    if ((tid & 63) == 0) {
        int w = tid >> 6;
        rA[w] = area; rI[w] = si; rJ[w] = sj;
        rmi[w] = mini; rMi[w] = maxi; rmj[w] = minj; rMj[w] = maxj;
    }
    __syncthreads();
    if (tid == 0) {
        area = rA[0] + rA[1] + rA[2] + rA[3];
        si   = rI[0] + rI[1] + rI[2] + rI[3];
        sj   = rJ[0] + rJ[1] + rJ[2] + rJ[3];
        mini = min(min(rmi[0], rmi[1]), min(rmi[2], rmi[3]));
        maxi = max(max(rMi[0], rMi[1]), max(rMi[2], rMi[3]));
        minj = min(min(rmj[0], rmj[1]), min(rmj[2], rmj[3]));
        maxj = max(max(rMj[0], rMj[1]), max(rMj[2], rMj[3]));
        float st[6];
        if (area > 0.f) {
            float safe = fmaxf(area, 1.f);
            float cy = si / safe, cx = sj / safe;
            float h = (float)(maxi - mini), ww = (float)(maxj - minj);
            st[0] = cy / 256.f; st[1] = cx / 256.f;
            st[2] = h / 256.f;  st[3] = ww / 256.f;
            st[4] = area / 65536.f; st[5] = h * ww / 65536.f;
        } else {
            for (int k = 0; k < 6; ++k) st[k] = 0.f;
        }
        for (int k = 0; k < 6; ++k) stats[b * 6 + k] = st[k];
    }
}

// ---------------------------------------------------------------------------
// Fused MLP head. One block per batch row, 256 threads.
// ---------------------------------------------------------------------------
__global__ __launch_bounds__(256) void head_k(
    const float* __restrict__ local_acc,  // B x 128 (spatial sums)
    const float* __restrict__ shape_acc,  // B x 64  (spatial sums)
    const float* __restrict__ stats,      // B x 6
    const float* __restrict__ gw, const float* __restrict__ gb,
    const float* __restrict__ fpw1, const float* __restrict__ fpb1,
    const float* __restrict__ fpw2, const float* __restrict__ fpb2,
    const float* __restrict__ ffw1, const float* __restrict__ ffb1,
    const float* __restrict__ ffw2, const float* __restrict__ ffb2,
    float* __restrict__ out)              // B x 256
{
    int b = blockIdx.x, tid = threadIdx.x;
    __shared__ float comb[80], hid1[128], sf[64], fused[192], hid2[256];
    constexpr float INV = 1.f / 4096.f;

    if (tid < 64) comb[tid] = shape_acc[b * 64 + tid] * INV;
    if (tid >= 64 && tid < 80) {
        int co = tid - 64;
        float s = gb[co];
        for (int k = 0; k < 6; ++k) s += gw[co * 6 + k] * stats[b * 6 + k];
        comb[tid] = s;
    }
    __syncthreads();
    if (tid < 128) {
        float s = fpb1[tid];
        for (int k = 0; k < 80; ++k) s += fpw1[tid * 80 + k] * comb[k];
        hid1[tid] = fmaxf(s, 0.f);
    }
    __syncthreads();
    if (tid < 64) {
        float s = fpb2[tid];
        for (int k = 0; k < 128; ++k) s += fpw2[tid * 128 + k] * hid1[k];
        sf[tid] = s;
    }
    if (tid < 128) fused[tid] = local_acc[b * 128 + tid] * INV;
    __syncthreads();
    if (tid >= 128 && tid < 192) fused[tid] = sf[tid - 128];
    __syncthreads();
    {
        float s = ffb1[tid];
        for (int k = 0; k < 192; ++k) s += ffw1[tid * 192 + k] * fused[k];
        hid2[tid] = fmaxf(s, 0.f);
    }
    __syncthreads();
    {
        float s = ffb2[tid];
        for (int k = 0; k < 256; ++k) s += ffw2[tid * 256 + k] * hid2[k];
        out[(size_t)b * 256 + tid] = s;
    }
}

// ---------------------------------------------------------------------------
extern "C" void kernel_launch(void* const* d_in, const int* in_sizes, int n_in,
                              void* d_out, int out_size, void* d_ws, size_t ws_size,
                              hipStream_t stream)
{
    const float* x    = (const float*)d_in[0];
    const float* mask = (const float*)d_in[1];
    const float* lw1 = (const float*)d_in[2];  const float* lb1 = (const float*)d_in[3];
    const float* lw2 = (const float*)d_in[4];  const float* lb2 = (const float*)d_in[5];
    const float* lw3 = (const float*)d_in[6];  const float* lb3 = (const float*)d_in[7];
    const float* sw1 = (const float*)d_in[8];  const float* sb1 = (const float*)d_in[9];
    const float* sw2 = (const float*)d_in[10]; const float* sb2 = (const float*)d_in[11];
    const float* sw3 = (const float*)d_in[12]; const float* sb3 = (const float*)d_in[13];
    const float* gw  = (const float*)d_in[14]; const float* gb  = (const float*)d_in[15];
    const float* fpw1 = (const float*)d_in[16]; const float* fpb1 = (const float*)d_in[17];
    const float* fpw2 = (const float*)d_in[18]; const float* fpb2 = (const float*)d_in[19];
    const float* ffw1 = (const float*)d_in[20]; const float* ffb1 = (const float*)d_in[21];
    const float* ffw2 = (const float*)d_in[22]; const float* ffb2 = (const float*)d_in[23];
    float* out = (float*)d_out;

    char* ws = (char*)d_ws;
    _Float16* bufA   = (_Float16*)ws;                     // 67,108,864 B ([B][128][128][<=32])
    _Float16* bufB   = (_Float16*)(ws + 67108864);        // 33,554,432 B ([B][64][64][<=64])
    float* local_acc = (float*)(ws + 100663296);          // 32,768 B
    float* shape_acc = (float*)(ws + 100696064);          // 16,384 B
    float* statsb    = (float*)(ws + 100712448);          // 2,048 B
    _Float16* W1L    = (_Float16*)(ws + 100714496);       // 2,048 B
    _Float16* W1S    = (_Float16*)(ws + 100716544);       // 2,048 B
    _Float16* wp2    = (_Float16*)(ws + 100718592);       // 36,864 B
    _Float16* wp3    = (_Float16*)(ws + 100755456);       // 147,456 B
    _Float16* wp2s   = (_Float16*)(ws + 100902912);       // 18,432 B
    _Float16* wp3s   = (_Float16*)(ws + 100921344);       // 36,864 B

    // weight prep + accumulator zeroing
    prep_w1_k<32><<<4, 256, 0, stream>>>(lw1, W1L);
    prep_w1_k<16><<<2, 256, 0, stream>>>(sw1, W1S);
    prep_wN_k<32, 64>  <<<72,  256, 0, stream>>>(lw2, wp2);
    prep_wN_k<64, 128> <<<288, 256, 0, stream>>>(lw3, wp3);
    prep_wN_k<16, 32>  <<<36,  256, 0, stream>>>(sw2, wp2s);
    prep_wN_k<32, 64>  <<<72,  256, 0, stream>>>(sw3, wp3s);
    hipMemsetAsync(local_acc, 0, 32768 + 16384, stream);

    // ---- local branch ----
    conv1_mfma_k<32><<<64 * 256, 256, 0, stream>>>(x, W1L, lb1, bufA);
    convN_mfma_k<32, 64, 128, true> <<<64 * 64 * 2, 256, 0, stream>>>(bufA, wp2, lb2, bufB);
    convN_mfma_k<64, 128, 64, false><<<64 * 16 * 4, 256, 0, stream>>>(bufB, wp3, lb3, local_acc);

    // ---- shape branch (reuses bufA/bufB sequentially) ----
    conv1_mfma_k<16><<<64 * 256, 256, 0, stream>>>(mask, W1S, sb1, bufA);
    convN_mfma_k<16, 32, 128, true> <<<64 * 64 * 1, 256, 0, stream>>>(bufA, wp2s, sb2, bufB);
    convN_mfma_k<32, 64, 64, false> <<<64 * 16 * 2, 256, 0, stream>>>(bufB, wp3s, sb3, shape_acc);

    // ---- global stats + head ----
    stats_k<<<64, 256, 0, stream>>>(mask, statsb);
    head_k<<<64, 256, 0, stream>>>(local_acc, shape_acc, statsb, gw, gb,
                                   fpw1, fpb1, fpw2, fpb2, ffw1, ffb1, ffw2, ffb2, out);
}

// Round 5
// 272.788 us; speedup vs baseline: 9.0692x; 1.0572x over previous
//
#include <hip/hip_runtime.h>

typedef _Float16 f16x8 __attribute__((ext_vector_type(8)));
typedef float    f32x4 __attribute__((ext_vector_type(4)));

static __device__ inline f16x8 f16x8_zero() {
    f16x8 v;
#pragma unroll
    for (int j = 0; j < 8; ++j) v[j] = (_Float16)0.f;
    return v;
}

// ---------------------------------------------------------------------------
// Weight prep conv1 (CIN=1, split-f16 full precision), see round-3 comment.
// ---------------------------------------------------------------------------
template<int COUT>
__global__ __launch_bounds__(256) void prep_w1_k(const float* __restrict__ w,
                                                 _Float16* __restrict__ dst)
{
    int t = blockIdx.x * 256 + threadIdx.x;
    if (t >= COUT * 32) return;
    int co = t >> 5, k = t & 31;
    _Float16 r = (_Float16)0.f;
    if (k < 27) {
        int q = k / 9, tap = k - q * 9;
        float wv = w[co * 9 + tap];
        _Float16 hi = (_Float16)wv;
        r = (q == 2) ? (_Float16)(wv - (float)hi) : hi;
    }
    dst[t] = r;
}

// ---------------------------------------------------------------------------
// Weight prep convN: fp32 OIHW -> f16 [ch][tap][COUT][32k] (zero-pad past CIN)
// ---------------------------------------------------------------------------
template<int CIN, int COUT>
__global__ __launch_bounds__(256) void prep_wN_k(const float* __restrict__ w,
                                                 _Float16* __restrict__ dst)
{
    constexpr int NCH = (CIN + 31) / 32;
    int t = blockIdx.x * 256 + threadIdx.x;
    if (t >= NCH * 9 * COUT * 32) return;
    int k = t & 31;
    int r = t >> 5;
    int co = r % COUT; r /= COUT;
    int tap = r % 9;
    int ch  = r / 9;
    int ci  = ch * 32 + k;
    dst[t] = (ci < CIN) ? (_Float16)w[(co * CIN + ci) * 9 + tap] : (_Float16)0.f;
}

// ---------------------------------------------------------------------------
// conv1: CIN=1 fp32 in [B][256][256] -> conv+bias+relu+pool -> f16 NHWC.
// K=27 split-f16 (fp32-exact). 256 thr / 4 waves = 16x16 conv-pixel tile.
// ---------------------------------------------------------------------------
template<int COUT>
__global__ __launch_bounds__(256) void conv1_mfma_k(
    const float* __restrict__ in, const _Float16* __restrict__ W1,
    const float* __restrict__ bias, _Float16* __restrict__ out)
{
    constexpr int H = 256, TILES = H / 16, NT = COUT / 16;

    __shared__ _Float16 sHL[972];   // [0,324)=hi, [324,648)=lo, [648,972)=0

    int blk  = blockIdx.x;
    int b    = blk / (TILES * TILES);
    int tile = blk % (TILES * TILES);
    int ty0  = (tile / TILES) * 16;
    int tx0  = (tile % TILES) * 16;
    int tid  = threadIdx.x;
    int wv   = tid >> 6, l = tid & 63, cl = l & 15, kg = l >> 4;

    for (int idx = tid; idx < 324; idx += 256) {
        int row = idx / 18, col = idx - row * 18;
        int gy = ty0 - 1 + row, gx = tx0 - 1 + col;
        float v = 0.f;
        if ((unsigned)gy < (unsigned)H && (unsigned)gx < (unsigned)H)
            v = in[((size_t)b * H + gy) * H + gx];
        _Float16 hi = (_Float16)v;
        sHL[idx]       = hi;
        sHL[324 + idx] = (_Float16)(v - (float)hi);
        sHL[648 + idx] = (_Float16)0.f;
    }
    __syncthreads();

    int off8[8];
#pragma unroll
    for (int j = 0; j < 8; ++j) {
        int k = kg * 8 + j;
        int q = k / 9;
        int t = k - q * 9;
        int region = (q == 1) ? 1 : ((q == 3) ? 2 : 0);
        off8[j] = region * 324 + (t / 3) * 18 + (t % 3) + cl;
    }

    f16x8 bf[NT];
#pragma unroll
    for (int nt = 0; nt < NT; ++nt)
        bf[nt] = *(const f16x8*)&W1[(nt * 16 + cl) * 32 + kg * 8];

    f32x4 acc[4][NT];
#pragma unroll
    for (int i = 0; i < 4; ++i)
#pragma unroll
        for (int nt = 0; nt < NT; ++nt) acc[i][nt] = (f32x4){0.f, 0.f, 0.f, 0.f};

#pragma unroll
    for (int i = 0; i < 4; ++i) {
        int R = wv * 4 + i;
        f16x8 af;
#pragma unroll
        for (int j = 0; j < 8; ++j) af[j] = sHL[off8[j] + R * 18];
#pragma unroll
        for (int nt = 0; nt < NT; ++nt)
            acc[i][nt] = __builtin_amdgcn_mfma_f32_16x16x32_f16(af, bf[nt], acc[i][nt], 0, 0, 0);
    }

    int py0 = ty0 >> 1, px0 = tx0 >> 1;
#pragma unroll
    for (int nt = 0; nt < NT; ++nt) {
        float bv = bias[nt * 16 + cl];
#pragma unroll
        for (int i2 = 0; i2 < 2; ++i2)
#pragma unroll
            for (int j2 = 0; j2 < 2; ++j2) {
                float m = fmaxf(fmaxf(acc[2 * i2][nt][2 * j2], acc[2 * i2][nt][2 * j2 + 1]),
                                fmaxf(acc[2 * i2 + 1][nt][2 * j2], acc[2 * i2 + 1][nt][2 * j2 + 1]));
                float v = fmaxf(m + bv, 0.f);
                out[(((size_t)b * 128 + py0 + wv * 2 + i2) * 128 + px0 + kg * 2 + j2) * COUT
                    + nt * 16 + cl] = (_Float16)v;
            }
    }
}

// ---------------------------------------------------------------------------
// convN: f16 NHWC in -> conv3x3+bias+relu -> pool (f16 NHWC) or spatial-sum
// (f32 atomic). 64 co per block (NT<=4). A staged in LDS, 18 hoisted frags
// per chunk; W streamed per-lane from GLOBAL (coalesced 1KB/instr, L2-hot),
// double-buffered across taps -> LDS pipe carries only ~38 instr/wave/chunk
// vs 144 MFMA.
// ---------------------------------------------------------------------------
template<int CIN, int COUT, int H, bool POOL>
__global__ __launch_bounds__(256, 2) void convN_mfma_k(
    const _Float16* __restrict__ in, const _Float16* __restrict__ wp,
    const float* __restrict__ bias, void* __restrict__ outv)
{
    constexpr int TILES = H / 16;
    constexpr int NT    = (COUT >= 64) ? 4 : COUT / 16;
    constexpr int NG    = COUT / (NT * 16);
    constexpr int NCH   = (CIN + 31) / 32;
    constexpr int KU    = (CIN >= 32) ? 4 : CIN / 8;
    static_assert(H % 16 == 0 && COUT % 16 == 0, "");

    __shared__ _Float16 sA[324 * 40];     // 25,920 B

    int blk  = blockIdx.x;
    int b    = blk / (TILES * TILES * NG);
    int rem  = blk % (TILES * TILES * NG);
    int grp  = rem / (TILES * TILES);
    int tile = rem % (TILES * TILES);
    int ty0  = (tile / TILES) * 16;
    int tx0  = (tile % TILES) * 16;
    int tid  = threadIdx.x;
    int wv   = tid >> 6, l = tid & 63, cl = l & 15, kg = l >> 4;
    int cog0 = grp * NT * 16;

    f32x4 acc[4][NT];
#pragma unroll
    for (int i = 0; i < 4; ++i)
#pragma unroll
        for (int nt = 0; nt < NT; ++nt) acc[i][nt] = (f32x4){0.f, 0.f, 0.f, 0.f};

    for (int ch = 0; ch < NCH; ++ch) {
        if (ch) __syncthreads();
        // ---- stage A: 324 pos x 4 16B-units ----
        for (int u = tid; u < 1296; u += 256) {
            int pos = u >> 2, q = u & 3;
            int row = pos / 18, col = pos - row * 18;
            int gy = ty0 - 1 + row, gx = tx0 - 1 + col;
            f16x8 v = f16x8_zero();
            if (q < KU && (unsigned)gy < (unsigned)H && (unsigned)gx < (unsigned)H)
                v = *(const f16x8*)&in[(((size_t)b * H + gy) * H + gx) * CIN + ch * 32 + q * 8];
            *(f16x8*)&sA[pos * 40 + q * 8] = v;
        }
        __syncthreads();

        // ---- hoisted A fragments: rows wv*4 .. wv*4+5, dx 0..2 ----
        f16x8 a[6][3];
#pragma unroll
        for (int r = 0; r < 6; ++r)
#pragma unroll
            for (int dx = 0; dx < 3; ++dx)
                a[r][dx] = *(const f16x8*)&sA[((wv * 4 + r) * 18 + cl + dx) * 40 + kg * 8];

        // ---- W streamed from global, tap double-buffer ----
        const _Float16* wbase = wp + ((size_t)ch * 9 * COUT + cog0) * 32;
        f16x8 wreg[2][NT];
#pragma unroll
        for (int nt = 0; nt < NT; ++nt)
            wreg[0][nt] = *(const f16x8*)&wbase[(0 * COUT + nt * 16 + cl) * 32 + kg * 8];

#pragma unroll
        for (int tap = 0; tap < 9; ++tap) {
            if (tap < 8) {
#pragma unroll
                for (int nt = 0; nt < NT; ++nt)
                    wreg[(tap + 1) & 1][nt] =
                        *(const f16x8*)&wbase[((tap + 1) * COUT + nt * 16 + cl) * 32 + kg * 8];
            }
            int dy = tap / 3, dx = tap - dy * 3;
#pragma unroll
            for (int i = 0; i < 4; ++i) {
                f16x8 af = a[i + dy][dx];
#pragma unroll
                for (int nt = 0; nt < NT; ++nt)
                    acc[i][nt] = __builtin_amdgcn_mfma_f32_16x16x32_f16(
                        af, wreg[tap & 1][nt], acc[i][nt], 0, 0, 0);
            }
        }
    }

    if (POOL) {
        _Float16* out = (_Float16*)outv;
        constexpr int HO = H / 2;
        int py0 = ty0 >> 1, px0 = tx0 >> 1;
#pragma unroll
        for (int nt = 0; nt < NT; ++nt) {
            float bv = bias[cog0 + nt * 16 + cl];
#pragma unroll
            for (int i2 = 0; i2 < 2; ++i2)
#pragma unroll
                for (int j2 = 0; j2 < 2; ++j2) {
                    float m = fmaxf(fmaxf(acc[2 * i2][nt][2 * j2], acc[2 * i2][nt][2 * j2 + 1]),
                                    fmaxf(acc[2 * i2 + 1][nt][2 * j2], acc[2 * i2 + 1][nt][2 * j2 + 1]));
                    float v = fmaxf(m + bv, 0.f);
                    out[(((size_t)b * HO + py0 + wv * 2 + i2) * HO + px0 + kg * 2 + j2) * COUT
                        + cog0 + nt * 16 + cl] = (_Float16)v;
                }
        }
    } else {
        float* accum = (float*)outv;
#pragma unroll
        for (int nt = 0; nt < NT; ++nt) {
            float bv = bias[cog0 + nt * 16 + cl];
            float s = 0.f;
#pragma unroll
            for (int i = 0; i < 4; ++i)
#pragma unroll
                for (int r = 0; r < 4; ++r)
                    s += fmaxf(acc[i][nt][r] + bv, 0.f);
            s += __shfl_xor(s, 16); s += __shfl_xor(s, 32);
            if (kg == 0) atomicAdd(&accum[b * COUT + cog0 + nt * 16 + cl], s);
        }
    }
}

// ---------------------------------------------------------------------------
// global_stats partial: 4 blocks per image, atomic merge into raw arrays.
// ---------------------------------------------------------------------------
__global__ __launch_bounds__(256) void stats_k(const float* __restrict__ mask,
    float* __restrict__ areaA, float* __restrict__ siA, float* __restrict__ sjA,
    int* __restrict__ miniA, int* __restrict__ maxiA,
    int* __restrict__ minjA, int* __restrict__ maxjA)
{
    int blk = blockIdx.x, b = blk >> 2, part = blk & 3;
    int tid = threadIdx.x;
    const float4* m4 = (const float4*)(mask + (size_t)b * 65536);
    float area = 0.f, si = 0.f, sj = 0.f;
    int mini = 1 << 20, maxi = -1, minj = 1 << 20, maxj = -1;
    for (int i4 = part * 4096 + tid; i4 < (part + 1) * 4096; i4 += 256) {
        float4 v = m4[i4];
        int base = i4 * 4;
        int i = base >> 8, j0 = base & 255;
        float vv[4] = {v.x, v.y, v.z, v.w};
#pragma unroll
        for (int q = 0; q < 4; ++q) {
            if (vv[q] != 0.f) {
                int j = j0 + q;
                area += 1.f; si += (float)i; sj += (float)j;
                mini = min(mini, i); maxi = max(maxi, i);
                minj = min(minj, j); maxj = max(maxj, j);
            }
        }
    }
#pragma unroll
    for (int off = 32; off > 0; off >>= 1) {
        area += __shfl_down(area, off);
        si   += __shfl_down(si, off);
        sj   += __shfl_down(sj, off);
        mini  = min(mini, __shfl_down(mini, off));
        maxi  = max(maxi, __shfl_down(maxi, off));
        minj  = min(minj, __shfl_down(minj, off));
        maxj  = max(maxj, __shfl_down(maxj, off));
    }
    __shared__ float rA[4], rI[4], rJ[4];
    __shared__ int   rmi[4], rMi[4], rmj[4], rMj[4];
    if ((tid & 63) == 0) {
        int w = tid >> 6;
        rA[w] = area; rI[w] = si; rJ[w] = sj;
        rmi[w] = mini; rMi[w] = maxi; rmj[w] = minj; rMj[w] = maxj;
    }
    __syncthreads();
    if (tid == 0) {
        area = rA[0] + rA[1] + rA[2] + rA[3];
        si   = rI[0] + rI[1] + rI[2] + rI[3];
        sj   = rJ[0] + rJ[1] + rJ[2] + rJ[3];
        mini = min(min(rmi[0], rmi[1]), min(rmi[2], rmi[3]));
        maxi = max(max(rMi[0], rMi[1]), max(rMi[2], rMi[3]));
        minj = min(min(rmj[0], rmj[1]), min(rmj[2], rmj[3]));
        maxj = max(max(rMj[0], rMj[1]), max(rMj[2], rMj[3]));
        if (area > 0.f) {
            atomicAdd(&areaA[b], area);
            atomicAdd(&siA[b], si);
            atomicAdd(&sjA[b], sj);
            atomicMin(&miniA[b], mini);
            atomicMax(&maxiA[b], maxi);
            atomicMin(&minjA[b], minj);
            atomicMax(&maxjA[b], maxj);
        }
    }
}

// ---------------------------------------------------------------------------
// Fused MLP head (computes global_stats features inline from raw sums).
// ---------------------------------------------------------------------------
__global__ __launch_bounds__(256) void head_k(
    const float* __restrict__ local_acc,  // B x 128 (spatial sums)
    const float* __restrict__ shape_acc,  // B x 64  (spatial sums)
    const float* __restrict__ areaA, const float* __restrict__ siA,
    const float* __restrict__ sjA,
    const int* __restrict__ miniA, const int* __restrict__ maxiA,
    const int* __restrict__ minjA, const int* __restrict__ maxjA,
    const float* __restrict__ gw, const float* __restrict__ gb,
    const float* __restrict__ fpw1, const float* __restrict__ fpb1,
    const float* __restrict__ fpw2, const float* __restrict__ fpb2,
    const float* __restrict__ ffw1, const float* __restrict__ ffb1,
    const float* __restrict__ ffw2, const float* __restrict__ ffb2,
    float* __restrict__ out)              // B x 256
{
    int b = blockIdx.x, tid = threadIdx.x;
    __shared__ float comb[80], hid1[128], sf[64], fused[192], hid2[256];
    constexpr float INV = 1.f / 4096.f;

    if (tid < 64) comb[tid] = shape_acc[b * 64 + tid] * INV;
    if (tid >= 64 && tid < 80) {
        int co = tid - 64;
        float st[6] = {0.f, 0.f, 0.f, 0.f, 0.f, 0.f};
        float area = areaA[b];
        if (area > 0.f) {
            float safe = fmaxf(area, 1.f);
            float h  = (float)(maxiA[b] - miniA[b]);
            float w2 = (float)(maxjA[b] - minjA[b]);
            st[0] = (siA[b] / safe) / 256.f;
            st[1] = (sjA[b] / safe) / 256.f;
            st[2] = h / 256.f; st[3] = w2 / 256.f;
            st[4] = area / 65536.f; st[5] = h * w2 / 65536.f;
        }
        float s = gb[co];
        for (int k = 0; k < 6; ++k) s += gw[co * 6 + k] * st[k];
        comb[tid] = s;
    }
    __syncthreads();
    if (tid < 128) {
        float s = fpb1[tid];
        for (int k = 0; k < 80; ++k) s += fpw1[tid * 80 + k] * comb[k];
        hid1[tid] = fmaxf(s, 0.f);
    }
    __syncthreads();
    if (tid < 64) {
        float s = fpb2[tid];
        for (int k = 0; k < 128; ++k) s += fpw2[tid * 128 + k] * hid1[k];
        sf[tid] = s;
    }
    if (tid < 128) fused[tid] = local_acc[b * 128 + tid] * INV;
    __syncthreads();
    if (tid >= 128 && tid < 192) fused[tid] = sf[tid - 128];
    __syncthreads();
    {
        float s = ffb1[tid];
        for (int k = 0; k < 192; ++k) s += ffw1[tid * 192 + k] * fused[k];
        hid2[tid] = fmaxf(s, 0.f);
    }
    __syncthreads();
    {
        float s = ffb2[tid];
        for (int k = 0; k < 256; ++k) s += ffw2[tid * 256 + k] * hid2[k];
        out[(size_t)b * 256 + tid] = s;
    }
}

// ---------------------------------------------------------------------------
extern "C" void kernel_launch(void* const* d_in, const int* in_sizes, int n_in,
                              void* d_out, int out_size, void* d_ws, size_t ws_size,
                              hipStream_t stream)
{
    const float* x    = (const float*)d_in[0];
    const float* mask = (const float*)d_in[1];
    const float* lw1 = (const float*)d_in[2];  const float* lb1 = (const float*)d_in[3];
    const float* lw2 = (const float*)d_in[4];  const float* lb2 = (const float*)d_in[5];
    const float* lw3 = (const float*)d_in[6];  const float* lb3 = (const float*)d_in[7];
    const float* sw1 = (const float*)d_in[8];  const float* sb1 = (const float*)d_in[9];
    const float* sw2 = (const float*)d_in[10]; const float* sb2 = (const float*)d_in[11];
    const float* sw3 = (const float*)d_in[12]; const float* sb3 = (const float*)d_in[13];
    const float* gw  = (const float*)d_in[14]; const float* gb  = (const float*)d_in[15];
    const float* fpw1 = (const float*)d_in[16]; const float* fpb1 = (const float*)d_in[17];
    const float* fpw2 = (const float*)d_in[18]; const float* fpb2 = (const float*)d_in[19];
    const float* ffw1 = (const float*)d_in[20]; const float* ffb1 = (const float*)d_in[21];
    const float* ffw2 = (const float*)d_in[22]; const float* ffb2 = (const float*)d_in[23];
    float* out = (float*)d_out;

    char* ws = (char*)d_ws;
    _Float16* bufA   = (_Float16*)ws;                     // 67,108,864 B
    _Float16* bufB   = (_Float16*)(ws + 67108864);        // 33,554,432 B
    size_t base = 100663296;
    float* local_acc = (float*)(ws + base);               // 32,768
    float* shape_acc = (float*)(ws + base + 32768);       // 16,384
    float* areaA     = (float*)(ws + base + 49152);       // 256
    float* siA       = (float*)(ws + base + 49408);       // 256
    float* sjA       = (float*)(ws + base + 49664);       // 256
    int*   maxiA     = (int*)  (ws + base + 49920);       // 256
    int*   maxjA     = (int*)  (ws + base + 50176);       // 256
    int*   miniA     = (int*)  (ws + base + 50432);       // 256
    int*   minjA     = (int*)  (ws + base + 50688);       // 256
    _Float16* W1L    = (_Float16*)(ws + base + 51200);    // 2,048
    _Float16* W1S    = (_Float16*)(ws + base + 53248);    // 2,048
    _Float16* wp2    = (_Float16*)(ws + base + 55296);    // 36,864
    _Float16* wp3    = (_Float16*)(ws + base + 92160);    // 147,456
    _Float16* wp2s   = (_Float16*)(ws + base + 239616);   // 18,432
    _Float16* wp3s   = (_Float16*)(ws + base + 258048);   // 36,864

    // accumulators + zero-init stats (area/si/sj/maxi/maxj=0), mini/minj=huge
    hipMemsetAsync(local_acc, 0, 50432, stream);
    hipMemsetAsync(ws + base + 50432, 0x7f, 512, stream);

    // weight prep
    prep_w1_k<32><<<4, 256, 0, stream>>>(lw1, W1L);
    prep_w1_k<16><<<2, 256, 0, stream>>>(sw1, W1S);
    prep_wN_k<32, 64>  <<<72,  256, 0, stream>>>(lw2, wp2);
    prep_wN_k<64, 128> <<<288, 256, 0, stream>>>(lw3, wp3);
    prep_wN_k<16, 32>  <<<36,  256, 0, stream>>>(sw2, wp2s);
    prep_wN_k<32, 64>  <<<72,  256, 0, stream>>>(sw3, wp3s);

    // ---- local branch ----
    conv1_mfma_k<32><<<64 * 256, 256, 0, stream>>>(x, W1L, lb1, bufA);
    convN_mfma_k<32, 64, 128, true> <<<64 * 64, 256, 0, stream>>>(bufA, wp2, lb2, bufB);
    convN_mfma_k<64, 128, 64, false><<<64 * 16 * 2, 256, 0, stream>>>(bufB, wp3, lb3, local_acc);

    // ---- shape branch ----
    conv1_mfma_k<16><<<64 * 256, 256, 0, stream>>>(mask, W1S, sb1, bufA);
    convN_mfma_k<16, 32, 128, true> <<<64 * 64, 256, 0, stream>>>(bufA, wp2s, sb2, bufB);
    convN_mfma_k<32, 64, 64, false> <<<64 * 16, 256, 0, stream>>>(bufB, wp3s, sb3, shape_acc);

    // ---- global stats + head ----
    stats_k<<<256, 256, 0, stream>>>(mask, areaA, siA, sjA, miniA, maxiA, minjA, maxjA);
    head_k<<<64, 256, 0, stream>>>(local_acc, shape_acc, areaA, siA, sjA,
                                   miniA, maxiA, minjA, maxjA, gw, gb,
                                   fpw1, fpb1, fpw2, fpb2, ffw1, ffb1, ffw2, ffb2, out);
}

// Round 6
// 261.150 us; speedup vs baseline: 9.4734x; 1.0446x over previous
//
#include <hip/hip_runtime.h>

typedef _Float16 f16x8 __attribute__((ext_vector_type(8)));
typedef float    f32x4 __attribute__((ext_vector_type(4)));

static __device__ inline f16x8 f16x8_zero() {
    f16x8 v;
#pragma unroll
    for (int j = 0; j < 8; ++j) v[j] = (_Float16)0.f;
    return v;
}

// ---------------------------------------------------------------------------
// Weight prep conv1 (CIN=1, split-f16 full precision):
// k=0..8: hi(w); 9..17: hi(w); 18..26: lo(w); 27..31: 0, pairing with
// A rows {hi, lo, hi} -> x_hi*w_hi + x_lo*w_hi + x_hi*w_lo (error ~2^-22).
// ---------------------------------------------------------------------------
template<int COUT>
__global__ __launch_bounds__(256) void prep_w1_k(const float* __restrict__ w,
                                                 _Float16* __restrict__ dst)
{
    int t = blockIdx.x * 256 + threadIdx.x;
    if (t >= COUT * 32) return;
    int co = t >> 5, k = t & 31;
    _Float16 r = (_Float16)0.f;
    if (k < 27) {
        int q = k / 9, tap = k - q * 9;
        float wv = w[co * 9 + tap];
        _Float16 hi = (_Float16)wv;
        r = (q == 2) ? (_Float16)(wv - (float)hi) : hi;
    }
    dst[t] = r;
}

// ---------------------------------------------------------------------------
// Weight prep convN: fp32 OIHW -> f16 [ch][tap][COUT][32k] (zero-pad past CIN)
// ---------------------------------------------------------------------------
template<int CIN, int COUT>
__global__ __launch_bounds__(256) void prep_wN_k(const float* __restrict__ w,
                                                 _Float16* __restrict__ dst)
{
    constexpr int NCH = (CIN + 31) / 32;
    int t = blockIdx.x * 256 + threadIdx.x;
    if (t >= NCH * 9 * COUT * 32) return;
    int k = t & 31;
    int r = t >> 5;
    int co = r % COUT; r /= COUT;
    int tap = r % 9;
    int ch  = r / 9;
    int ci  = ch * 32 + k;
    dst[t] = (ci < CIN) ? (_Float16)w[(co * CIN + ci) * 9 + tap] : (_Float16)0.f;
}

// ---------------------------------------------------------------------------
// conv1: CIN=1 fp32 in [B][256][256] -> conv+bias+relu+pool -> f16 NHWC.
// K=27 split-f16 (fp32-exact). 256 thr / 4 waves = 16x16 conv-pixel tile.
// ---------------------------------------------------------------------------
template<int COUT>
__global__ __launch_bounds__(256) void conv1_mfma_k(
    const float* __restrict__ in, const _Float16* __restrict__ W1,
    const float* __restrict__ bias, _Float16* __restrict__ out)
{
    constexpr int H = 256, TILES = H / 16, NT = COUT / 16;

    __shared__ _Float16 sHL[972];   // [0,324)=hi, [324,648)=lo, [648,972)=0

    int blk  = blockIdx.x;
    int b    = blk / (TILES * TILES);
    int tile = blk % (TILES * TILES);
    int ty0  = (tile / TILES) * 16;
    int tx0  = (tile % TILES) * 16;
    int tid  = threadIdx.x;
    int wv   = tid >> 6, l = tid & 63, cl = l & 15, kg = l >> 4;

    for (int idx = tid; idx < 324; idx += 256) {
        int row = idx / 18, col = idx - row * 18;
        int gy = ty0 - 1 + row, gx = tx0 - 1 + col;
        float v = 0.f;
        if ((unsigned)gy < (unsigned)H && (unsigned)gx < (unsigned)H)
            v = in[((size_t)b * H + gy) * H + gx];
        _Float16 hi = (_Float16)v;
        sHL[idx]       = hi;
        sHL[324 + idx] = (_Float16)(v - (float)hi);
        sHL[648 + idx] = (_Float16)0.f;
    }
    __syncthreads();

    int off8[8];
#pragma unroll
    for (int j = 0; j < 8; ++j) {
        int k = kg * 8 + j;
        int q = k / 9;
        int t = k - q * 9;
        int region = (q == 1) ? 1 : ((q == 3) ? 2 : 0);
        off8[j] = region * 324 + (t / 3) * 18 + (t % 3) + cl;
    }

    f16x8 bf[NT];
#pragma unroll
    for (int nt = 0; nt < NT; ++nt)
        bf[nt] = *(const f16x8*)&W1[(nt * 16 + cl) * 32 + kg * 8];

    f32x4 acc[4][NT];
#pragma unroll
    for (int i = 0; i < 4; ++i)
#pragma unroll
        for (int nt = 0; nt < NT; ++nt) acc[i][nt] = (f32x4){0.f, 0.f, 0.f, 0.f};

#pragma unroll
    for (int i = 0; i < 4; ++i) {
        int R = wv * 4 + i;
        f16x8 af;
#pragma unroll
        for (int j = 0; j < 8; ++j) af[j] = sHL[off8[j] + R * 18];
#pragma unroll
        for (int nt = 0; nt < NT; ++nt)
            acc[i][nt] = __builtin_amdgcn_mfma_f32_16x16x32_f16(af, bf[nt], acc[i][nt], 0, 0, 0);
    }

    int py0 = ty0 >> 1, px0 = tx0 >> 1;
#pragma unroll
    for (int nt = 0; nt < NT; ++nt) {
        float bv = bias[nt * 16 + cl];
#pragma unroll
        for (int i2 = 0; i2 < 2; ++i2)
#pragma unroll
            for (int j2 = 0; j2 < 2; ++j2) {
                float m = fmaxf(fmaxf(acc[2 * i2][nt][2 * j2], acc[2 * i2][nt][2 * j2 + 1]),
                                fmaxf(acc[2 * i2 + 1][nt][2 * j2], acc[2 * i2 + 1][nt][2 * j2 + 1]));
                float v = fmaxf(m + bv, 0.f);
                out[(((size_t)b * 128 + py0 + wv * 2 + i2) * 128 + px0 + kg * 2 + j2) * COUT
                    + nt * 16 + cl] = (_Float16)v;
            }
    }
}

// ---------------------------------------------------------------------------
// convN v3: f16 NHWC in -> conv3x3+bias+relu -> pool (f16 NHWC) or
// spatial-sum (f32 atomic).
// Block: 256 thr / 4 waves; tile = 32 rows x 16 cols; each WAVE owns 8 rows
// x 64 co (M8N4, acc=128 f32/lane, 2 waves/SIMD) -> one 36KB W fetch feeds
// 288 MFMAs (2x the r5 arithmetic intensity; vmem was the cap).
// A in LDS [34][18][44-pad]; W per-lane from global (L2-hot), 3-slot
// rotation prefetched 2 taps ahead.
// ---------------------------------------------------------------------------
template<int CIN, int COUT, int H, bool POOL>
__global__ __launch_bounds__(256, 2) void convN_mfma_k(
    const _Float16* __restrict__ in, const _Float16* __restrict__ wp,
    const float* __restrict__ bias, void* __restrict__ outv)
{
    constexpr int TX  = H / 16, TY = H / 32, TT = TX * TY;
    constexpr int NT  = (COUT >= 64) ? 4 : COUT / 16;
    constexpr int NG  = COUT / (NT * 16);
    constexpr int NCH = (CIN + 31) / 32;
    constexpr int KU  = (CIN >= 32) ? 4 : CIN / 8;
    constexpr int LDA = 44;                 // pad: pos*22 mod 32 spreads banks
    static_assert(H % 32 == 0 && COUT % 16 == 0, "");

    __shared__ _Float16 sA[612 * LDA];      // 34 rows x 18 cols -> 53,856 B

    int blk  = blockIdx.x;
    int b    = blk / (TT * NG);
    int rem  = blk % (TT * NG);
    int grp  = rem / TT;
    int tile = rem % TT;
    int ty0  = (tile / TX) * 32;
    int tx0  = (tile % TX) * 16;
    int tid  = threadIdx.x;
    int wv   = tid >> 6, l = tid & 63, cl = l & 15, kg = l >> 4;
    int cog0 = grp * NT * 16;

    f32x4 acc[8][NT];
#pragma unroll
    for (int i = 0; i < 8; ++i)
#pragma unroll
        for (int nt = 0; nt < NT; ++nt) acc[i][nt] = (f32x4){0.f, 0.f, 0.f, 0.f};

    for (int ch = 0; ch < NCH; ++ch) {
        if (ch) __syncthreads();
        // ---- stage A: 612 pos x 4 16B-units ----
        for (int u = tid; u < 2448; u += 256) {
            int pos = u >> 2, q = u & 3;
            int row = pos / 18, col = pos - row * 18;
            int gy = ty0 - 1 + row, gx = tx0 - 1 + col;
            f16x8 v = f16x8_zero();
            if (q < KU && (unsigned)gy < (unsigned)H && (unsigned)gx < (unsigned)H)
                v = *(const f16x8*)&in[(((size_t)b * H + gy) * H + gx) * CIN + ch * 32 + q * 8];
            *(f16x8*)&sA[pos * LDA + q * 8] = v;
        }
        __syncthreads();

        // ---- W: 3-slot rotation, prefetch 2 taps ahead ----
        const _Float16* wbase = wp + ((size_t)ch * 9 * COUT + cog0) * 32;
        f16x8 wreg[3][NT];
#pragma unroll
        for (int nt = 0; nt < NT; ++nt) {
            wreg[0][nt] = *(const f16x8*)&wbase[(0 * COUT + nt * 16 + cl) * 32 + kg * 8];
            wreg[1][nt] = *(const f16x8*)&wbase[(1 * COUT + nt * 16 + cl) * 32 + kg * 8];
        }

#pragma unroll
        for (int tap = 0; tap < 9; ++tap) {
            if (tap < 7) {
#pragma unroll
                for (int nt = 0; nt < NT; ++nt)
                    wreg[(tap + 2) % 3][nt] =
                        *(const f16x8*)&wbase[((tap + 2) * COUT + nt * 16 + cl) * 32 + kg * 8];
            }
            int dy = tap / 3, dx = tap - dy * 3;
            f16x8 af[8];
#pragma unroll
            for (int i = 0; i < 8; ++i)
                af[i] = *(const f16x8*)&sA[((wv * 8 + i + dy) * 18 + cl + dx) * LDA + kg * 8];
#pragma unroll
            for (int i = 0; i < 8; ++i)
#pragma unroll
                for (int nt = 0; nt < NT; ++nt)
                    acc[i][nt] = __builtin_amdgcn_mfma_f32_16x16x32_f16(
                        af[i], wreg[tap % 3][nt], acc[i][nt], 0, 0, 0);
        }
    }

    if (POOL) {
        _Float16* out = (_Float16*)outv;
        constexpr int HO = H / 2;
        int py0 = ty0 >> 1, px0 = tx0 >> 1;
#pragma unroll
        for (int nt = 0; nt < NT; ++nt) {
            float bv = bias[cog0 + nt * 16 + cl];
#pragma unroll
            for (int i2 = 0; i2 < 4; ++i2)
#pragma unroll
                for (int j2 = 0; j2 < 2; ++j2) {
                    float m = fmaxf(fmaxf(acc[2 * i2][nt][2 * j2], acc[2 * i2][nt][2 * j2 + 1]),
                                    fmaxf(acc[2 * i2 + 1][nt][2 * j2], acc[2 * i2 + 1][nt][2 * j2 + 1]));
                    float v = fmaxf(m + bv, 0.f);
                    out[(((size_t)b * HO + py0 + wv * 4 + i2) * HO + px0 + kg * 2 + j2) * COUT
                        + cog0 + nt * 16 + cl] = (_Float16)v;
                }
        }
    } else {
        float* accum = (float*)outv;
#pragma unroll
        for (int nt = 0; nt < NT; ++nt) {
            float bv = bias[cog0 + nt * 16 + cl];
            float s = 0.f;
#pragma unroll
            for (int i = 0; i < 8; ++i)
#pragma unroll
                for (int r = 0; r < 4; ++r)
                    s += fmaxf(acc[i][nt][r] + bv, 0.f);
            s += __shfl_xor(s, 16); s += __shfl_xor(s, 32);
            if (kg == 0) atomicAdd(&accum[b * COUT + cog0 + nt * 16 + cl], s);
        }
    }
}

// ---------------------------------------------------------------------------
// global_stats partial: 4 blocks per image, atomic merge into raw arrays.
// ---------------------------------------------------------------------------
__global__ __launch_bounds__(256) void stats_k(const float* __restrict__ mask,
    float* __restrict__ areaA, float* __restrict__ siA, float* __restrict__ sjA,
    int* __restrict__ miniA, int* __restrict__ maxiA,
    int* __restrict__ minjA, int* __restrict__ maxjA)
{
    int blk = blockIdx.x, b = blk >> 2, part = blk & 3;
    int tid = threadIdx.x;
    const float4* m4 = (const float4*)(mask + (size_t)b * 65536);
    float area = 0.f, si = 0.f, sj = 0.f;
    int mini = 1 << 20, maxi = -1, minj = 1 << 20, maxj = -1;
    for (int i4 = part * 4096 + tid; i4 < (part + 1) * 4096; i4 += 256) {
        float4 v = m4[i4];
        int base = i4 * 4;
        int i = base >> 8, j0 = base & 255;
        float vv[4] = {v.x, v.y, v.z, v.w};
#pragma unroll
        for (int q = 0; q < 4; ++q) {
            if (vv[q] != 0.f) {
                int j = j0 + q;
                area += 1.f; si += (float)i; sj += (float)j;
                mini = min(mini, i); maxi = max(maxi, i);
                minj = min(minj, j); maxj = max(maxj, j);
            }
        }
    }
#pragma unroll
    for (int off = 32; off > 0; off >>= 1) {
        area += __shfl_down(area, off);
        si   += __shfl_down(si, off);
        sj   += __shfl_down(sj, off);
        mini  = min(mini, __shfl_down(mini, off));
        maxi  = max(maxi, __shfl_down(maxi, off));
        minj  = min(minj, __shfl_down(minj, off));
        maxj  = max(maxj, __shfl_down(maxj, off));
    }
    __shared__ float rA[4], rI[4], rJ[4];
    __shared__ int   rmi[4], rMi[4], rmj[4], rMj[4];
    if ((tid & 63) == 0) {
        int w = tid >> 6;
        rA[w] = area; rI[w] = si; rJ[w] = sj;
        rmi[w] = mini; rMi[w] = maxi; rmj[w] = minj; rMj[w] = maxj;
    }
    __syncthreads();
    if (tid == 0) {
        area = rA[0] + rA[1] + rA[2] + rA[3];
        si   = rI[0] + rI[1] + rI[2] + rI[3];
        sj   = rJ[0] + rJ[1] + rJ[2] + rJ[3];
        mini = min(min(rmi[0], rmi[1]), min(rmi[2], rmi[3]));
        maxi = max(max(rMi[0], rMi[1]), max(rMi[2], rMi[3]));
        minj = min(min(rmj[0], rmj[1]), min(rmj[2], rmj[3]));
        maxj = max(max(rMj[0], rMj[1]), max(rMj[2], rMj[3]));
        if (area > 0.f) {
            atomicAdd(&areaA[b], area);
            atomicAdd(&siA[b], si);
            atomicAdd(&sjA[b], sj);
            atomicMin(&miniA[b], mini);
            atomicMax(&maxiA[b], maxi);
            atomicMin(&minjA[b], minj);
            atomicMax(&maxjA[b], maxj);
        }
    }
}

// ---------------------------------------------------------------------------
// Fused MLP head (computes global_stats features inline from raw sums).
// ---------------------------------------------------------------------------
__global__ __launch_bounds__(256) void head_k(
    const float* __restrict__ local_acc,  // B x 128 (spatial sums)
    const float* __restrict__ shape_acc,  // B x 64  (spatial sums)
    const float* __restrict__ areaA, const float* __restrict__ siA,
    const float* __restrict__ sjA,
    const int* __restrict__ miniA, const int* __restrict__ maxiA,
    const int* __restrict__ minjA, const int* __restrict__ maxjA,
    const float* __restrict__ gw, const float* __restrict__ gb,
    const float* __restrict__ fpw1, const float* __restrict__ fpb1,
    const float* __restrict__ fpw2, const float* __restrict__ fpb2,
    const float* __restrict__ ffw1, const float* __restrict__ ffb1,
    const float* __restrict__ ffw2, const float* __restrict__ ffb2,
    float* __restrict__ out)              // B x 256
{
    int b = blockIdx.x, tid = threadIdx.x;
    __shared__ float comb[80], hid1[128], sf[64], fused[192], hid2[256];
    constexpr float INV = 1.f / 4096.f;

    if (tid < 64) comb[tid] = shape_acc[b * 64 + tid] * INV;
    if (tid >= 64 && tid < 80) {
        int co = tid - 64;
        float st[6] = {0.f, 0.f, 0.f, 0.f, 0.f, 0.f};
        float area = areaA[b];
        if (area > 0.f) {
            float safe = fmaxf(area, 1.f);
            float h  = (float)(maxiA[b] - miniA[b]);
            float w2 = (float)(maxjA[b] - minjA[b]);
            st[0] = (siA[b] / safe) / 256.f;
            st[1] = (sjA[b] / safe) / 256.f;
            st[2] = h / 256.f; st[3] = w2 / 256.f;
            st[4] = area / 65536.f; st[5] = h * w2 / 65536.f;
        }
        float s = gb[co];
        for (int k = 0; k < 6; ++k) s += gw[co * 6 + k] * st[k];
        comb[tid] = s;
    }
    __syncthreads();
    if (tid < 128) {
        float s = fpb1[tid];
        for (int k = 0; k < 80; ++k) s += fpw1[tid * 80 + k] * comb[k];
        hid1[tid] = fmaxf(s, 0.f);
    }
    __syncthreads();
    if (tid < 64) {
        float s = fpb2[tid];
        for (int k = 0; k < 128; ++k) s += fpw2[tid * 128 + k] * hid1[k];
        sf[tid] = s;
    }
    if (tid < 128) fused[tid] = local_acc[b * 128 + tid] * INV;
    __syncthreads();
    if (tid >= 128 && tid < 192) fused[tid] = sf[tid - 128];
    __syncthreads();
    {
        float s = ffb1[tid];
        for (int k = 0; k < 192; ++k) s += ffw1[tid * 192 + k] * fused[k];
        hid2[tid] = fmaxf(s, 0.f);
    }
    __syncthreads();
    {
        float s = ffb2[tid];
        for (int k = 0; k < 256; ++k) s += ffw2[tid * 256 + k] * hid2[k];
        out[(size_t)b * 256 + tid] = s;
    }
}

// ---------------------------------------------------------------------------
extern "C" void kernel_launch(void* const* d_in, const int* in_sizes, int n_in,
                              void* d_out, int out_size, void* d_ws, size_t ws_size,
                              hipStream_t stream)
{
    const float* x    = (const float*)d_in[0];
    const float* mask = (const float*)d_in[1];
    const float* lw1 = (const float*)d_in[2];  const float* lb1 = (const float*)d_in[3];
    const float* lw2 = (const float*)d_in[4];  const float* lb2 = (const float*)d_in[5];
    const float* lw3 = (const float*)d_in[6];  const float* lb3 = (const float*)d_in[7];
    const float* sw1 = (const float*)d_in[8];  const float* sb1 = (const float*)d_in[9];
    const float* sw2 = (const float*)d_in[10]; const float* sb2 = (const float*)d_in[11];
    const float* sw3 = (const float*)d_in[12]; const float* sb3 = (const float*)d_in[13];
    const float* gw  = (const float*)d_in[14]; const float* gb  = (const float*)d_in[15];
    const float* fpw1 = (const float*)d_in[16]; const float* fpb1 = (const float*)d_in[17];
    const float* fpw2 = (const float*)d_in[18]; const float* fpb2 = (const float*)d_in[19];
    const float* ffw1 = (const float*)d_in[20]; const float* ffb1 = (const float*)d_in[21];
    const float* ffw2 = (const float*)d_in[22]; const float* ffb2 = (const float*)d_in[23];
    float* out = (float*)d_out;

    char* ws = (char*)d_ws;
    _Float16* bufA   = (_Float16*)ws;                     // 67,108,864 B
    _Float16* bufB   = (_Float16*)(ws + 67108864);        // 33,554,432 B
    size_t base = 100663296;
    float* local_acc = (float*)(ws + base);               // 32,768
    float* shape_acc = (float*)(ws + base + 32768);       // 16,384
    float* areaA     = (float*)(ws + base + 49152);       // 256
    float* siA       = (float*)(ws + base + 49408);       // 256
    float* sjA       = (float*)(ws + base + 49664);       // 256
    int*   maxiA     = (int*)  (ws + base + 49920);       // 256
    int*   maxjA     = (int*)  (ws + base + 50176);       // 256
    int*   miniA     = (int*)  (ws + base + 50432);       // 256
    int*   minjA     = (int*)  (ws + base + 50688);       // 256
    _Float16* W1L    = (_Float16*)(ws + base + 51200);    // 2,048
    _Float16* W1S    = (_Float16*)(ws + base + 53248);    // 2,048
    _Float16* wp2    = (_Float16*)(ws + base + 55296);    // 36,864
    _Float16* wp3    = (_Float16*)(ws + base + 92160);    // 147,456
    _Float16* wp2s   = (_Float16*)(ws + base + 239616);   // 18,432
    _Float16* wp3s   = (_Float16*)(ws + base + 258048);   // 36,864

    // accumulators + zero-init stats (area/si/sj/maxi/maxj=0), mini/minj=huge
    hipMemsetAsync(local_acc, 0, 50432, stream);
    hipMemsetAsync(ws + base + 50432, 0x7f, 512, stream);

    // weight prep
    prep_w1_k<32><<<4, 256, 0, stream>>>(lw1, W1L);
    prep_w1_k<16><<<2, 256, 0, stream>>>(sw1, W1S);
    prep_wN_k<32, 64>  <<<72,  256, 0, stream>>>(lw2, wp2);
    prep_wN_k<64, 128> <<<288, 256, 0, stream>>>(lw3, wp3);
    prep_wN_k<16, 32>  <<<36,  256, 0, stream>>>(sw2, wp2s);
    prep_wN_k<32, 64>  <<<72,  256, 0, stream>>>(sw3, wp3s);

    // ---- local branch ----
    conv1_mfma_k<32><<<64 * 256, 256, 0, stream>>>(x, W1L, lb1, bufA);
    convN_mfma_k<32, 64, 128, true> <<<2048, 256, 0, stream>>>(bufA, wp2, lb2, bufB);
    convN_mfma_k<64, 128, 64, false><<<1024, 256, 0, stream>>>(bufB, wp3, lb3, local_acc);

    // ---- shape branch ----
    conv1_mfma_k<16><<<64 * 256, 256, 0, stream>>>(mask, W1S, sb1, bufA);
    convN_mfma_k<16, 32, 128, true> <<<2048, 256, 0, stream>>>(bufA, wp2s, sb2, bufB);
    convN_mfma_k<32, 64, 64, false> <<<512,  256, 0, stream>>>(bufB, wp3s, sb3, shape_acc);

    // ---- global stats + head ----
    stats_k<<<256, 256, 0, stream>>>(mask, areaA, siA, sjA, miniA, maxiA, minjA, maxjA);
    head_k<<<64, 256, 0, stream>>>(local_acc, shape_acc, areaA, siA, sjA,
                                   miniA, maxiA, minjA, maxjA, gw, gb,
                                   fpw1, fpb1, fpw2, fpb2, ffw1, ffb1, ffw2, ffb2, out);
}